// Round 2
// baseline (7243.904 us; speedup 1.0000x reference)
//
#include <hip/hip_runtime.h>

typedef unsigned short u16;
using bf16x8 = __attribute__((ext_vector_type(8))) short;
using f32x4  = __attribute__((ext_vector_type(4))) float;

__device__ __forceinline__ float bf2f(u16 u) {
  union { unsigned int i; float f; } v; v.i = ((unsigned int)u) << 16; return v.f;
}
__device__ __forceinline__ u16 f2bf(float f) {
  union { float f; unsigned int i; } v; v.f = f;
  unsigned int r = v.i + 0x7fffu + ((v.i >> 16) & 1u);  // RNE
  return (u16)(r >> 16);
}

// async global->LDS, 16B per lane. LDS side must be wave-uniform base + lane*16.
__device__ __forceinline__ void async_copy16(const u16* g, u16* l) {
  __builtin_amdgcn_global_load_lds(
      (const __attribute__((address_space(1))) void*)g,
      (__attribute__((address_space(3))) void*)l, 16, 0, 0);
}

// ---------------------------------------------------------------------------
// m97-style bf16 GEMM: C[N,M] = A[N,K] * B[M,K]^T  (B given row-major [M,K])
// 128x128 tile, BK=32, 4 waves each computing 64x64 via 4x4 of 16x16x32 MFMA.
// Batched via blockIdx.z with two-level (outer,inner) strides.
// OUTMODE: 0 = fp32 store, 1 = bf16 store, 2 = fp32 C += rowscale[row]*val,
//          3 = scatter: atomicAdd(C[gidx[row]*ldc+col], rowscale[gidx[row]]*val), guarded by *gcnt
//          4 = dense split-K accumulate: atomicAdd(C[row*ldc+col], rowscale[row]*val)
// GA: gather A rows through gidx (count-guarded; padded rows use token 0)
// ACT: 0 none, 1 relu, 2 exact gelu.  All dims must be multiples of tile.
// ---------------------------------------------------------------------------
template<int ACT, int OUTMODE, int HAS_BIAS, int GA>
__global__ __launch_bounds__(256)
void gemm_tile(const u16* __restrict__ A, const u16* __restrict__ B,
               void* __restrict__ C,
               const float* __restrict__ bias,
               const float* __restrict__ rowscale, int rs_stride,
               const int* __restrict__ gidx, const int* __restrict__ gcnt,
               int bias_zi0,
               int lda, int ldb, int ldc, int K, int inner,
               long long sAo, long long sAi, long long sBo, long long sBi,
               long long sCo, long long sCi)
{
  __shared__ u16 Als[128 * 32];
  __shared__ u16 Bls[128 * 32];

  const int tid  = threadIdx.x;
  const int lane = tid & 63;
  const int wave = tid >> 6;

  const int z  = blockIdx.z;
  const int zo = z / inner;
  const int zi = z - zo * inner;

  const long long n0 = (long long)blockIdx.x * 128;
  const long long m0 = (long long)blockIdx.y * 128;

  int cnt = 0x7fffffff;
  if (GA || OUTMODE == 3) {
    cnt = *gcnt;
    if (n0 >= cnt) return;      // uniform early exit for padded grid
  }

  const u16* Ab = A + zo * sAo + zi * sAi;
  const u16* Bb = B + zo * sBo + zi * sBi;

  // staging: 512 16B-chunks per tile; thread handles chunks tid and tid+256
  const int c0 = tid, c1 = tid + 256;
  const int rA0 = c0 >> 2, kA0 = (c0 & 3) * 8;
  const int rA1 = c1 >> 2, kA1 = (c1 & 3) * 8;

  long long arow0 = n0 + rA0, arow1 = n0 + rA1;
  if (GA) {
    arow0 = (arow0 < cnt) ? (long long)gidx[arow0] : 0;
    arow1 = (arow1 < cnt) ? (long long)gidx[arow1] : 0;
  }
  const u16* gA0 = Ab + arow0 * lda + kA0;
  const u16* gA1 = Ab + arow1 * lda + kA1;
  const u16* gB0 = Bb + (m0 + rA0) * ldb + kA0;
  const u16* gB1 = Bb + (m0 + rA1) * ldb + kA1;

  const int fr = lane & 15;   // A-row / B-row / C-col within 16x16 frag
  const int fq = lane >> 4;   // quad: k-offset fq*8, C-row fq*4
  const u16* Ard = &Als[(((wave >> 1) * 64) + fr) * 32 + fq * 8];
  const u16* Brd = &Bls[(((wave & 1) * 64) + fr) * 32 + fq * 8];

  f32x4 acc[4][4] = {};

  for (int kt = 0; kt < K; kt += 32) {
    async_copy16(gA0, &Als[c0 * 8]);
    async_copy16(gA1, &Als[c1 * 8]);
    async_copy16(gB0, &Bls[c0 * 8]);
    async_copy16(gB1, &Bls[c1 * 8]);
    gA0 += 32; gA1 += 32; gB0 += 32; gB1 += 32;
    __syncthreads();   // drains vmcnt -> staged tile visible

    bf16x8 af[4], bfv[4];
#pragma unroll
    for (int i = 0; i < 4; ++i) af[i]  = *(const bf16x8*)(Ard + i * (16 * 32));
#pragma unroll
    for (int j = 0; j < 4; ++j) bfv[j] = *(const bf16x8*)(Brd + j * (16 * 32));
#pragma unroll
    for (int i = 0; i < 4; ++i)
#pragma unroll
      for (int j = 0; j < 4; ++j)
        acc[i][j] = __builtin_amdgcn_mfma_f32_16x16x32_bf16(af[i], bfv[j], acc[i][j], 0, 0, 0);
    __syncthreads();   // before next overwrite
  }

  const long long cb = zo * sCo + zi * sCi;
  const int wr = (wave >> 1) * 64;
  const int wc = (wave & 1) * 64;
#pragma unroll
  for (int i = 0; i < 4; ++i) {
#pragma unroll
    for (int r = 0; r < 4; ++r) {
      const long long row = n0 + wr + i * 16 + fq * 4 + r;
      float rs = 0.f;
      long long crow = row;
      bool ok = true;
      if (OUTMODE == 2 || OUTMODE == 4) rs = rowscale[row * (long long)rs_stride];
      if (OUTMODE == 3) {
        ok = row < cnt;
        const int tok = ok ? gidx[row] : 0;
        crow = tok;
        rs = ok ? rowscale[(long long)tok * rs_stride] : 0.f;
      }
#pragma unroll
      for (int j = 0; j < 4; ++j) {
        const long long col = m0 + wc + j * 16 + fr;
        float v = acc[i][j][r];
        if (HAS_BIAS) { if (!bias_zi0 || zi == 0) v += bias[col]; }
        if (ACT == 1) v = fmaxf(v, 0.f);
        if (ACT == 2) v = 0.5f * v * (1.f + erff(v * 0.70710678118654752f));
        const long long idx = cb + crow * ldc + col;
        if (OUTMODE == 0)      ((float*)C)[idx] = v;
        else if (OUTMODE == 1) ((u16*)C)[idx] = f2bf(v);
        else if (OUTMODE == 2) ((float*)C)[idx] += rs * v;
        else if (OUTMODE == 4) atomicAdd(&((float*)C)[idx], rs * v);
        else if (ok)           atomicAdd(&((float*)C)[idx], rs * v);
      }
    }
  }
}

template<int ACT, int OUT, int BIAS>
static inline void run_gemm(hipStream_t st,
    const u16* A, const u16* B, void* C, const float* bias,
    const float* rowscale, int rs_stride,
    int N, int M, int K, int lda, int ldb, int ldc,
    int batch, int inner,
    long long sAo, long long sAi, long long sBo, long long sBi,
    long long sCo, long long sCi)
{
  dim3 g(N / 128, M / 128, batch);
  gemm_tile<ACT, OUT, BIAS, 0><<<g, dim3(256), 0, st>>>(
      A, B, C, bias, rowscale, rs_stride, nullptr, nullptr, 0,
      lda, ldb, ldc, K, inner, sAo, sAi, sBo, sBi, sCo, sCi);
}

// ---------------------------------------------------------------------------
// elementwise / small kernels
// ---------------------------------------------------------------------------
__global__ void cast_bf16_k(const float* __restrict__ s, u16* __restrict__ d, long long n)
{
  long long i = (long long)blockIdx.x * blockDim.x + threadIdx.x;
  const long long stride = (long long)gridDim.x * blockDim.x;
  for (; i < n; i += stride) d[i] = f2bf(s[i]);
}

__global__ void transpose_f32_k(const float* __restrict__ s, float* __restrict__ d,
                                int rows, int cols)
{
  int i = blockIdx.x * blockDim.x + threadIdx.x;
  if (i < rows * cols) { int r = i / cols, c = i - r * cols; d[c * rows + r] = s[i]; }
}

// patch gather + relu(t@w1T)+relu(.@w2T) + sinusoidal PE -> z bf16 [16384,128]
__global__ __launch_bounds__(64)
void tokenizer_k(const float* __restrict__ x, const float* __restrict__ w1T,
                 const float* __restrict__ b1, const float* __restrict__ w2T,
                 const float* __restrict__ b2, u16* __restrict__ z)
{
  const int token = blockIdx.x;             // b*1024 + s
  const int b = token >> 10, s = token & 1023;
  const int ph = s >> 5, pw = s & 31;
  const int lane = threadIdx.x;
  __shared__ float t[320];
  __shared__ float z1[64];
  const int py = lane >> 3, px = lane & 7;
  const float* xp = x + (size_t)b * 5 * 65536 + (size_t)(ph * 8 + py) * 256 + pw * 8 + px;
#pragma unroll
  for (int c = 0; c < 5; ++c) t[c * 64 + lane] = xp[(size_t)c * 65536];
  __syncthreads();
  float acc = b1[lane];
  for (int k = 0; k < 320; ++k) acc = fmaf(t[k], w1T[k * 64 + lane], acc);
  z1[lane] = fmaxf(acc, 0.f);
  __syncthreads();
  float a0 = b2[lane], a1 = b2[lane + 64];
  for (int k = 0; k < 64; ++k) {
    const float zv = z1[k];
    a0 = fmaf(zv, w2T[k * 128 + lane], a0);
    a1 = fmaf(zv, w2T[k * 128 + lane + 64], a1);
  }
  a0 = fmaxf(a0, 0.f); a1 = fmaxf(a1, 0.f);
  const float fs = (float)s;
  const int d0 = lane, d1 = lane + 64;
  const float div0 = expf(-logf(10000.f) * (float)(d0 & ~1) / 128.f);
  const float div1 = expf(-logf(10000.f) * (float)(d1 & ~1) / 128.f);
  const float pe0 = (d0 & 1) ? cosf(fs * div0) : sinf(fs * div0);
  const float pe1 = (d1 & 1) ? cosf(fs * div1) : sinf(fs * div1);
  z[(size_t)token * 128 + d0] = f2bf(a0 + pe0);
  z[(size_t)token * 128 + d1] = f2bf(a1 + pe1);
}

// V slice of qkv -> vT[z=b*4+h][d][s], LDS-tiled transpose
__global__ void transpose_v_k(const u16* __restrict__ qkv, u16* __restrict__ vT)
{
  __shared__ u16 tile[32][33];
  const int z = blockIdx.z;
  const int b = z >> 2, hh = z & 3;
  const int s0 = blockIdx.x * 32, d0 = blockIdx.y * 32;
  const int tx = threadIdx.x;
  for (int i = threadIdx.y; i < 32; i += 8)
    tile[i][tx] = qkv[(long long)(b * 1024 + s0 + i) * 1536 + 1024 + hh * 128 + d0 + tx];
  __syncthreads();
  for (int j = threadIdx.y; j < 32; j += 8)
    vT[((long long)z * 128 + d0 + j) * 1024 + s0 + tx] = tile[tx][j];
}

// in-place row softmax (1024 cols, bf16), applies scale before softmax
__global__ __launch_bounds__(256)
void softmax_k(u16* __restrict__ P, float scale)
{
  const long long row = blockIdx.x;
  u16* p = P + row * 1024;
  const int tid = threadIdx.x;
  float v[4];
#pragma unroll
  for (int j = 0; j < 4; ++j) v[j] = bf2f(p[tid + j * 256]) * scale;
  __shared__ float red[256];
  float mx = fmaxf(fmaxf(v[0], v[1]), fmaxf(v[2], v[3]));
  red[tid] = mx; __syncthreads();
  for (int s = 128; s > 0; s >>= 1) { if (tid < s) red[tid] = fmaxf(red[tid], red[tid + s]); __syncthreads(); }
  mx = red[0]; __syncthreads();
  float sum = 0.f;
#pragma unroll
  for (int j = 0; j < 4; ++j) { v[j] = expf(v[j] - mx); sum += v[j]; }
  red[tid] = sum; __syncthreads();
  for (int s = 128; s > 0; s >>= 1) { if (tid < s) red[tid] += red[tid + s]; __syncthreads(); }
  const float inv = 1.f / red[0];
#pragma unroll
  for (int j = 0; j < 4; ++j) p[tid + j * 256] = f2bf(v[j] * inv);
}

// h = LN(h + a); writes h fp32 and bf16 copy
__global__ __launch_bounds__(256)
void ln_add_k(float* __restrict__ h, const float* __restrict__ a,
              const float* __restrict__ g, const float* __restrict__ b,
              u16* __restrict__ hbf)
{
  const long long t = blockIdx.x;
  const int tid = threadIdx.x;
  float* hp = h + t * 512;
  const float* ap = a + t * 512;
  const float x0 = hp[tid] + ap[tid];
  const float x1 = hp[tid + 256] + ap[tid + 256];
  __shared__ float r1[256], r2[256];
  r1[tid] = x0 + x1; r2[tid] = x0 * x0 + x1 * x1;
  __syncthreads();
  for (int s = 128; s > 0; s >>= 1) { if (tid < s) { r1[tid] += r1[tid + s]; r2[tid] += r2[tid + s]; } __syncthreads(); }
  const float mean = r1[0] * (1.f / 512.f);
  const float var  = r2[0] * (1.f / 512.f) - mean * mean;
  const float rstd = rsqrtf(var + 1e-5f);
  const float y0 = (x0 - mean) * rstd * g[tid] + b[tid];
  const float y1 = (x1 - mean) * rstd * g[tid + 256] + b[tid + 256];
  hp[tid] = y0; hp[tid + 256] = y1;
  hbf[t * 512 + tid] = f2bf(y0); hbf[t * 512 + tid + 256] = f2bf(y1);
}

// m = LN(h+macc, g1,b1); h = LN(h+m, g2,b2); writes h fp32 + bf16
__global__ __launch_bounds__(256)
void merge_ln_k(float* __restrict__ h, const float* __restrict__ macc,
                const float* __restrict__ g1, const float* __restrict__ b1,
                const float* __restrict__ g2, const float* __restrict__ b2,
                u16* __restrict__ hbf)
{
  const long long t = blockIdx.x;
  const int tid = threadIdx.x;
  float* hp = h + t * 512;
  const float* mp = macc + t * 512;
  const float hx0 = hp[tid], hx1 = hp[tid + 256];
  const float s0 = hx0 + mp[tid], s1 = hx1 + mp[tid + 256];
  __shared__ float r1[256], r2[256];
  r1[tid] = s0 + s1; r2[tid] = s0 * s0 + s1 * s1;
  __syncthreads();
  for (int s = 128; s > 0; s >>= 1) { if (tid < s) { r1[tid] += r1[tid + s]; r2[tid] += r2[tid + s]; } __syncthreads(); }
  float mean = r1[0] * (1.f / 512.f);
  float var  = r2[0] * (1.f / 512.f) - mean * mean;
  float rstd = rsqrtf(var + 1e-5f);
  const float m0v = (s0 - mean) * rstd * g1[tid] + b1[tid];
  const float m1v = (s1 - mean) * rstd * g1[tid + 256] + b1[tid + 256];
  const float z0 = hx0 + m0v, z1 = hx1 + m1v;
  __syncthreads();
  r1[tid] = z0 + z1; r2[tid] = z0 * z0 + z1 * z1;
  __syncthreads();
  for (int s = 128; s > 0; s >>= 1) { if (tid < s) { r1[tid] += r1[tid + s]; r2[tid] += r2[tid + s]; } __syncthreads(); }
  mean = r1[0] * (1.f / 512.f);
  var  = r2[0] * (1.f / 512.f) - mean * mean;
  rstd = rsqrtf(var + 1e-5f);
  const float y0 = (z0 - mean) * rstd * g2[tid] + b2[tid];
  const float y1 = (z1 - mean) * rstd * g2[tid + 256] + b2[tid + 256];
  hp[tid] = y0; hp[tid + 256] = y1;
  hbf[t * 512 + tid] = f2bf(y0); hbf[t * 512 + tid + 256] = f2bf(y1);
}

// per-token: spec router softmax + top2-normalized comb[6]; shared softmax sp[2]
__global__ __launch_bounds__(64)
void router_k(const float* __restrict__ h, const float* __restrict__ sw,
              const float* __restrict__ hw, float* __restrict__ comb,
              float* __restrict__ sp)
{
  const long long t = blockIdx.x;
  const int lane = threadIdx.x;
  const float* hp = h + t * 512;
  float v[8];
#pragma unroll
  for (int j = 0; j < 8; ++j) v[j] = hp[lane + j * 64];

  float lg[6];
#pragma unroll
  for (int e = 0; e < 6; ++e) {
    const float* w = sw + e * 512;
    float d = 0.f;
#pragma unroll
    for (int j = 0; j < 8; ++j) d += v[j] * w[lane + j * 64];
#pragma unroll
    for (int off = 32; off > 0; off >>= 1) d += __shfl_xor(d, off);
    lg[e] = d;
  }
  float mx = lg[0];
#pragma unroll
  for (int e = 1; e < 6; ++e) mx = fmaxf(mx, lg[e]);
  float pp[6]; float sum = 0.f;
#pragma unroll
  for (int e = 0; e < 6; ++e) { pp[e] = expf(lg[e] - mx); sum += pp[e]; }
  const float inv = 1.f / sum;
#pragma unroll
  for (int e = 0; e < 6; ++e) pp[e] *= inv;

  int i1 = 0; float p1 = pp[0];
#pragma unroll
  for (int e = 1; e < 6; ++e) if (pp[e] > p1) { p1 = pp[e]; i1 = e; }   // ties -> lower idx
  int i2 = -1; float p2 = -1.f;
#pragma unroll
  for (int e = 0; e < 6; ++e) if (e != i1 && pp[e] > p2) { p2 = pp[e]; i2 = e; }
  const float den = 1.f / (p1 + p2 + 1e-9f);
  if (lane == 0) {
#pragma unroll
    for (int e = 0; e < 6; ++e)
      comb[t * 6 + e] = (e == i1) ? p1 * den : ((e == i2) ? p2 * den : 0.f);
  }

  float l0 = 0.f, l1 = 0.f;
#pragma unroll
  for (int j = 0; j < 8; ++j) {
    l0 += v[j] * hw[lane + j * 64];
    l1 += v[j] * hw[512 + lane + j * 64];
  }
#pragma unroll
  for (int off = 32; off > 0; off >>= 1) { l0 += __shfl_xor(l0, off); l1 += __shfl_xor(l1, off); }
  const float m2 = fmaxf(l0, l1);
  const float e0 = expf(l0 - m2), e1 = expf(l1 - m2);
  const float si = 1.f / (e0 + e1);
  if (lane == 0) { sp[t * 2 + 0] = e0 * si; sp[t * 2 + 1] = e1 * si; }
}

// per-expert token lists from comb (order within an expert is irrelevant)
__global__ __launch_bounds__(256)
void build_lists_k(const float* __restrict__ comb, int* __restrict__ cnt,
                   int* __restrict__ idx)
{
  const int t = blockIdx.x * blockDim.x + threadIdx.x;
  if (t >= 16384) return;
#pragma unroll
  for (int e = 0; e < 6; ++e) {
    if (comb[(long long)t * 6 + e] > 0.f) {
      const int pos = atomicAdd(&cnt[e], 1);
      idx[e * 16384 + pos] = t;
    }
  }
}

// mean over S then logits = pooled @ cls_w.T + cls_b
__global__ __launch_bounds__(256)
void pool_cls_k(const float* __restrict__ h, const float* __restrict__ cw,
                const float* __restrict__ cb, float* __restrict__ out)
{
  const int b = blockIdx.x;
  const int tid = threadIdx.x;
  const float* hp = h + (size_t)b * 1024 * 512;
  float s0 = 0.f, s1 = 0.f;
  for (int s = 0; s < 1024; ++s) {
    s0 += hp[(size_t)s * 512 + tid];
    s1 += hp[(size_t)s * 512 + tid + 256];
  }
  __shared__ float pooled[512];
  pooled[tid] = s0 * (1.f / 1024.f); pooled[tid + 256] = s1 * (1.f / 1024.f);
  __syncthreads();
  __shared__ float red[256];
  for (int c = 0; c < 2; ++c) {
    const float d = pooled[tid] * cw[c * 512 + tid] + pooled[tid + 256] * cw[c * 512 + tid + 256];
    red[tid] = d; __syncthreads();
    for (int s = 128; s > 0; s >>= 1) { if (tid < s) red[tid] += red[tid + s]; __syncthreads(); }
    if (tid == 0) out[b * 2 + c] = red[0] + cb[c];
    __syncthreads();
  }
}

// ---------------------------------------------------------------------------
extern "C" void kernel_launch(void* const* d_in, const int* in_sizes, int n_in,
                              void* d_out, int out_size, void* d_ws, size_t ws_size,
                              hipStream_t stream)
{
  (void)in_sizes; (void)n_in; (void)out_size; (void)ws_size;
  const float* x      = (const float*)d_in[0];
  const float* tok_w1 = (const float*)d_in[1];
  const float* tok_b1 = (const float*)d_in[2];
  const float* tok_w2 = (const float*)d_in[3];
  const float* tok_b2 = (const float*)d_in[4];
  const float* proj_w = (const float*)d_in[5];
  const float* proj_b = (const float*)d_in[6];
  const float* wqkv   = (const float*)d_in[7];
  const float* bqkv   = (const float*)d_in[8];
  const float* wo     = (const float*)d_in[9];
  const float* bo     = (const float*)d_in[10];
  const float* ln1_g  = (const float*)d_in[11];
  const float* ln1_b  = (const float*)d_in[12];
  const float* srw    = (const float*)d_in[13];
  const float* sfc1w  = (const float*)d_in[14];
  const float* sfc1b  = (const float*)d_in[15];
  const float* sfc2w  = (const float*)d_in[16];
  const float* sfc2b  = (const float*)d_in[17];
  const float* hrw    = (const float*)d_in[18];
  const float* hfc1w  = (const float*)d_in[19];
  const float* hfc1b  = (const float*)d_in[20];
  const float* hfc2w  = (const float*)d_in[21];
  const float* hfc2b  = (const float*)d_in[22];
  const float* lnm_g  = (const float*)d_in[23];
  const float* lnm_b  = (const float*)d_in[24];
  const float* ln2_g  = (const float*)d_in[25];
  const float* ln2_b  = (const float*)d_in[26];
  const float* cls_w  = (const float*)d_in[27];
  const float* cls_b  = (const float*)d_in[28];

  char* ws = (char*)d_ws;
  size_t off = 0;
  auto alloc = [&](size_t bytes) -> char* {
    char* p = ws + off;
    off = (off + bytes + 255) & ~(size_t)255;
    return p;
  };

  // bf16 weight copies (re-created every call; inputs restored each launch)
  u16* proj_bf = (u16*)alloc((size_t)512 * 128 * 2);
  u16* qkvw_bf = (u16*)alloc((size_t)4 * 1536 * 512 * 2);
  u16* wow_bf  = (u16*)alloc((size_t)4 * 512 * 512 * 2);
  u16* sfc1_bf = (u16*)alloc((size_t)4 * 6 * 2048 * 512 * 2);
  u16* sfc2_bf = (u16*)alloc((size_t)4 * 6 * 512 * 2048 * 2);
  u16* hfc1_bf = (u16*)alloc((size_t)4 * 2 * 2048 * 512 * 2);
  u16* hfc2_bf = (u16*)alloc((size_t)4 * 2 * 512 * 2048 * 2);
  float* w1T   = (float*)alloc((size_t)320 * 64 * 4);
  float* w2T   = (float*)alloc((size_t)64 * 128 * 4);
  u16* zbf     = (u16*)alloc((size_t)16384 * 128 * 2);
  float* h     = (float*)alloc((size_t)16384 * 512 * 4);
  u16* hbf     = (u16*)alloc((size_t)16384 * 512 * 2);
  u16* vT      = (u16*)alloc((size_t)64 * 128 * 1024 * 2);
  u16* abf     = (u16*)alloc((size_t)16384 * 512 * 2);
  int* cnt     = (int*)alloc((size_t)6 * 4);
  int* idx     = (int*)alloc((size_t)6 * 16384 * 4);
  // regionA (67MB): scores chunk (32 bh x 1024 x 1024 bf16) / wo-out fp32 / hid bf16
  char* regA   = alloc((size_t)32 * 1024 * 1024 * 2);
  // regionB (50MB): qkv bf16 [16384,1536] / (moe_acc fp32 + comb + sp)
  char* regB   = alloc((size_t)16384 * 1536 * 2);
  u16*   scores = (u16*)regA;
  float* af32   = (float*)regA;
  u16*   hid    = (u16*)regA;
  u16*   qkv    = (u16*)regB;
  float* macc   = (float*)regB;
  float* comb   = (float*)(regB + (size_t)16384 * 512 * 4);
  float* sp     = (float*)(regB + (size_t)16384 * 512 * 4 + (size_t)16384 * 6 * 4);

  // ---- weight prep ----
  cast_bf16_k<<<4096, 256, 0, stream>>>(proj_w, proj_bf, 65536LL);
  cast_bf16_k<<<4096, 256, 0, stream>>>(wqkv,   qkvw_bf, 3145728LL);
  cast_bf16_k<<<4096, 256, 0, stream>>>(wo,     wow_bf,  1048576LL);
  cast_bf16_k<<<4096, 256, 0, stream>>>(sfc1w,  sfc1_bf, 25165824LL);
  cast_bf16_k<<<4096, 256, 0, stream>>>(sfc2w,  sfc2_bf, 25165824LL);
  cast_bf16_k<<<4096, 256, 0, stream>>>(hfc1w,  hfc1_bf, 8388608LL);
  cast_bf16_k<<<4096, 256, 0, stream>>>(hfc2w,  hfc2_bf, 8388608LL);
  transpose_f32_k<<<(20480 + 255) / 256, 256, 0, stream>>>(tok_w1, w1T, 64, 320);
  transpose_f32_k<<<(8192 + 255) / 256, 256, 0, stream>>>(tok_w2, w2T, 128, 64);

  // ---- tokenizer + PE -> z, proj -> h ----
  tokenizer_k<<<16384, 64, 0, stream>>>(x, w1T, tok_b1, w2T, tok_b2, zbf);
  run_gemm<0, 0, 1>(stream, zbf, proj_bf, h, proj_b, nullptr, 0,
                    16384, 512, 128, 128, 128, 512, 1, 1, 0, 0, 0, 0, 0, 0);
  cast_bf16_k<<<4096, 256, 0, stream>>>(h, hbf, 8388608LL);

  for (int l = 0; l < 4; ++l) {
    // qkv
    run_gemm<0, 1, 1>(stream, hbf, qkvw_bf + (size_t)l * 1536 * 512, qkv,
                      bqkv + l * 1536, nullptr, 0,
                      16384, 1536, 512, 512, 512, 1536, 1, 1, 0, 0, 0, 0, 0, 0);
    transpose_v_k<<<dim3(32, 4, 64), dim3(32, 8), 0, stream>>>(qkv, vT);
    // attention in 2 half-batch chunks (caps score buffer at 67MB)
    for (int c = 0; c < 2; ++c) {
      const u16* qb = qkv + (size_t)c * 8 * 1024 * 1536;
      run_gemm<0, 1, 0>(stream, qb, qb + 512, scores, nullptr, nullptr, 0,
                        1024, 1024, 128, 1536, 1536, 1024, 32, 4,
                        1024LL * 1536, 128, 1024LL * 1536, 128,
                        4LL * 1024 * 1024, 1024LL * 1024);
      softmax_k<<<32768, 256, 0, stream>>>(scores, 0.08838834764831845f);
      run_gemm<0, 1, 0>(stream, scores, vT + (size_t)c * 8 * 4 * 128 * 1024,
                        abf + (size_t)c * 8 * 1024 * 512, nullptr, nullptr, 0,
                        1024, 128, 1024, 1024, 1024, 512, 32, 4,
                        4LL * 1024 * 1024, 1024LL * 1024,
                        4LL * 128 * 1024, 128LL * 1024,
                        1024LL * 512, 128);
    }
    // output projection (fp32, into regionA after scores are dead)
    run_gemm<0, 0, 1>(stream, abf, wow_bf + (size_t)l * 512 * 512, af32,
                      bo + l * 512, nullptr, 0,
                      16384, 512, 512, 512, 512, 512, 1, 1, 0, 0, 0, 0, 0, 0);
    hipMemsetAsync(macc, 0, (size_t)16384 * 512 * 4, stream);  // qkv dead now
    ln_add_k<<<16384, 256, 0, stream>>>(h, af32, ln1_g + l * 512, ln1_b + l * 512, hbf);
    router_k<<<16384, 64, 0, stream>>>(h, srw + (size_t)l * 6 * 512,
                                       hrw + (size_t)l * 2 * 512, comb, sp);
    hipMemsetAsync(cnt, 0, 6 * sizeof(int), stream);
    build_lists_k<<<64, 256, 0, stream>>>(comb, cnt, idx);
    // specific experts: sparse (top-2), gathered rows; identical math to ref
    for (int e = 0; e < 6; ++e) {
      const size_t wi = (size_t)(l * 6 + e);
      // fc1: gather A rows by token list, gelu, bf16 store (position space)
      gemm_tile<2, 1, 1, 1><<<dim3(128, 16, 1), dim3(256), 0, stream>>>(
          hbf, sfc1_bf + wi * 2048 * 512, hid,
          sfc1b + wi * 2048, nullptr, 0, idx + e * 16384, cnt + e, 0,
          512, 512, 2048, 512, 1, 0, 0, 0, 0, 0, 0);
      // fc2: split-K (z=4, 512 K each), scatter atomicAdd into macc with comb weight
      gemm_tile<0, 3, 1, 0><<<dim3(128, 4, 4), dim3(256), 0, stream>>>(
          hid, sfc2_bf + wi * 512 * 2048, macc,
          sfc2b + wi * 512, comb + e, 6, idx + e * 16384, cnt + e, 1,
          2048, 2048, 512, 512, 4, 0, 512, 0, 512, 0, 0);
    }
    // shared experts (dense): fc1 as before; fc2 split-K (z=4) dense atomic accumulate
    for (int e = 0; e < 2; ++e) {
      const size_t wi = (size_t)(l * 2 + e);
      run_gemm<2, 1, 1>(stream, hbf, hfc1_bf + wi * 2048 * 512, hid,
                        hfc1b + wi * 2048, nullptr, 0,
                        16384, 2048, 512, 512, 512, 2048, 1, 1, 0, 0, 0, 0, 0, 0);
      gemm_tile<0, 4, 1, 0><<<dim3(128, 4, 4), dim3(256), 0, stream>>>(
          hid, hfc2_bf + wi * 512 * 2048, macc,
          hfc2b + wi * 512, sp + e, 2, nullptr, nullptr, 1,
          2048, 2048, 512, 512, 4, 0, 512, 0, 512, 0, 0);
    }
    merge_ln_k<<<16384, 256, 0, stream>>>(h, macc, lnm_g + l * 512, lnm_b + l * 512,
                                          ln2_g + l * 512, ln2_b + l * 512, hbf);
  }

  pool_cls_k<<<16, 256, 0, stream>>>(h, cls_w, cls_b, (float*)d_out);
}

// Round 4
// 6199.919 us; speedup vs baseline: 1.1684x; 1.1684x over previous
//
#include <hip/hip_runtime.h>

typedef unsigned short u16;
using bf16x8 = __attribute__((ext_vector_type(8))) short;
using f32x4  = __attribute__((ext_vector_type(4))) float;

__device__ __forceinline__ float bf2f(u16 u) {
  union { unsigned int i; float f; } v; v.i = ((unsigned int)u) << 16; return v.f;
}
__device__ __forceinline__ u16 f2bf(float f) {
  union { float f; unsigned int i; } v; v.f = f;
  unsigned int r = v.i + 0x7fffu + ((v.i >> 16) & 1u);  // RNE
  return (u16)(r >> 16);
}

// async global->LDS, 16B per lane. LDS side must be wave-uniform base + lane*16.
__device__ __forceinline__ void async_copy16(const u16* g, u16* l) {
  __builtin_amdgcn_global_load_lds(
      (const __attribute__((address_space(1))) void*)g,
      (__attribute__((address_space(3))) void*)l, 16, 0, 0);
}

// ---------------------------------------------------------------------------
// m97-style bf16 GEMM: C[N,M] = A[N,K] * B[M,K]^T  (B given row-major [M,K])
// 128x128 tile, BK=32, 4 waves each computing 64x64 via 4x4 of 16x16x32 MFMA.
// Batched via blockIdx.z with two-level (outer,inner) strides.
// OUTMODE: 0 = fp32 store, 1 = bf16 store, 2 = fp32 C += rowscale[row]*val,
//          3 = scatter: C[gidx[row]*ldc+col] += rowscale[gidx[row]]*val (atomic), guarded by *gcnt
// GA: gather A rows through gidx (count-guarded; padded rows use token 0)
// ACT: 0 none, 1 relu, 2 exact gelu.  All dims must be multiples of tile.
// ---------------------------------------------------------------------------
template<int ACT, int OUTMODE, int HAS_BIAS, int GA>
__global__ __launch_bounds__(256)
void gemm_tile(const u16* __restrict__ A, const u16* __restrict__ B,
               void* __restrict__ C,
               const float* __restrict__ bias,
               const float* __restrict__ rowscale, int rs_stride,
               const int* __restrict__ gidx, const int* __restrict__ gcnt,
               int bias_zi0,
               int lda, int ldb, int ldc, int K, int inner,
               long long sAo, long long sAi, long long sBo, long long sBi,
               long long sCo, long long sCi)
{
  __shared__ u16 Als[128 * 32];
  __shared__ u16 Bls[128 * 32];

  const int tid  = threadIdx.x;
  const int lane = tid & 63;
  const int wave = tid >> 6;

  const int z  = blockIdx.z;
  const int zo = z / inner;
  const int zi = z - zo * inner;

  const long long n0 = (long long)blockIdx.x * 128;
  const long long m0 = (long long)blockIdx.y * 128;

  int cnt = 0x7fffffff;
  if (GA || OUTMODE == 3) {
    cnt = *gcnt;
    if (n0 >= cnt) return;      // uniform early exit for padded grid
  }

  const u16* Ab = A + zo * sAo + zi * sAi;
  const u16* Bb = B + zo * sBo + zi * sBi;

  // staging: 512 16B-chunks per tile; thread handles chunks tid and tid+256
  const int c0 = tid, c1 = tid + 256;
  const int rA0 = c0 >> 2, kA0 = (c0 & 3) * 8;
  const int rA1 = c1 >> 2, kA1 = (c1 & 3) * 8;

  long long arow0 = n0 + rA0, arow1 = n0 + rA1;
  if (GA) {
    arow0 = (arow0 < cnt) ? (long long)gidx[arow0] : 0;
    arow1 = (arow1 < cnt) ? (long long)gidx[arow1] : 0;
  }
  const u16* gA0 = Ab + arow0 * lda + kA0;
  const u16* gA1 = Ab + arow1 * lda + kA1;
  const u16* gB0 = Bb + (m0 + rA0) * ldb + kA0;
  const u16* gB1 = Bb + (m0 + rA1) * ldb + kA1;

  const int fr = lane & 15;   // A-row / B-row / C-col within 16x16 frag
  const int fq = lane >> 4;   // quad: k-offset fq*8, C-row fq*4
  const u16* Ard = &Als[(((wave >> 1) * 64) + fr) * 32 + fq * 8];
  const u16* Brd = &Bls[(((wave & 1) * 64) + fr) * 32 + fq * 8];

  f32x4 acc[4][4] = {};

  for (int kt = 0; kt < K; kt += 32) {
    async_copy16(gA0, &Als[c0 * 8]);
    async_copy16(gA1, &Als[c1 * 8]);
    async_copy16(gB0, &Bls[c0 * 8]);
    async_copy16(gB1, &Bls[c1 * 8]);
    gA0 += 32; gA1 += 32; gB0 += 32; gB1 += 32;
    __syncthreads();   // drains vmcnt -> staged tile visible

    bf16x8 af[4], bfv[4];
#pragma unroll
    for (int i = 0; i < 4; ++i) af[i]  = *(const bf16x8*)(Ard + i * (16 * 32));
#pragma unroll
    for (int j = 0; j < 4; ++j) bfv[j] = *(const bf16x8*)(Brd + j * (16 * 32));
#pragma unroll
    for (int i = 0; i < 4; ++i)
#pragma unroll
      for (int j = 0; j < 4; ++j)
        acc[i][j] = __builtin_amdgcn_mfma_f32_16x16x32_bf16(af[i], bfv[j], acc[i][j], 0, 0, 0);
    __syncthreads();   // before next overwrite
  }

  const long long cb = zo * sCo + zi * sCi;
  const int wr = (wave >> 1) * 64;
  const int wc = (wave & 1) * 64;
#pragma unroll
  for (int i = 0; i < 4; ++i) {
#pragma unroll
    for (int r = 0; r < 4; ++r) {
      const long long row = n0 + wr + i * 16 + fq * 4 + r;
      float rs = 0.f;
      long long crow = row;
      bool ok = true;
      if (OUTMODE == 2) rs = rowscale[row * (long long)rs_stride];
      if (OUTMODE == 3) {
        ok = row < cnt;
        const int tok = ok ? gidx[row] : 0;
        crow = tok;
        rs = ok ? rowscale[(long long)tok * rs_stride] : 0.f;
      }
#pragma unroll
      for (int j = 0; j < 4; ++j) {
        const long long col = m0 + wc + j * 16 + fr;
        float v = acc[i][j][r];
        if (HAS_BIAS) { if (!bias_zi0 || zi == 0) v += bias[col]; }
        if (ACT == 1) v = fmaxf(v, 0.f);
        if (ACT == 2) v = 0.5f * v * (1.f + erff(v * 0.70710678118654752f));
        const long long idx = cb + crow * ldc + col;
        if (OUTMODE == 0)      ((float*)C)[idx] = v;
        else if (OUTMODE == 1) ((u16*)C)[idx] = f2bf(v);
        else if (OUTMODE == 2) ((float*)C)[idx] += rs * v;
        else if (ok)           atomicAdd(&((float*)C)[idx], rs * v);
      }
    }
  }
}

// ---------------------------------------------------------------------------
// 64x64-tile variant for skinny / low-grid GEMMs (4x the blocks of 128x128).
// 4 waves each compute a 32x32 quadrant via 2x2 of 16x16x32 MFMA. 8KB LDS.
// OUTMODE 3 here is a NON-atomic scatter += (rows unique within a dispatch;
// different experts are sequential dispatches on the same stream).
// ---------------------------------------------------------------------------
template<int ACT, int OUTMODE, int HAS_BIAS, int GA>
__global__ __launch_bounds__(256)
void gemm_tile64(const u16* __restrict__ A, const u16* __restrict__ B,
                 void* __restrict__ C,
                 const float* __restrict__ bias,
                 const float* __restrict__ rowscale, int rs_stride,
                 const int* __restrict__ gidx, const int* __restrict__ gcnt,
                 int bias_zi0,
                 int lda, int ldb, int ldc, int K, int inner,
                 long long sAo, long long sAi, long long sBo, long long sBi,
                 long long sCo, long long sCi)
{
  __shared__ u16 Als[64 * 32];
  __shared__ u16 Bls[64 * 32];

  const int tid  = threadIdx.x;
  const int lane = tid & 63;
  const int wave = tid >> 6;

  const int z  = blockIdx.z;
  const int zo = z / inner;
  const int zi = z - zo * inner;

  const long long n0 = (long long)blockIdx.x * 64;
  const long long m0 = (long long)blockIdx.y * 64;

  int cnt = 0x7fffffff;
  if (GA || OUTMODE == 3) {
    cnt = *gcnt;
    if (n0 >= cnt) return;      // uniform early exit for padded grid
  }

  const u16* Ab = A + zo * sAo + zi * sAi;
  const u16* Bb = B + zo * sBo + zi * sBi;

  // staging: 256 16B-chunks per tile; thread tid handles A chunk tid and B chunk tid
  const int rA = tid >> 2, kA = (tid & 3) * 8;

  long long arow = n0 + rA;
  if (GA) arow = (arow < cnt) ? (long long)gidx[arow] : 0;
  const u16* gA = Ab + arow * lda + kA;
  const u16* gB = Bb + (m0 + rA) * ldb + kA;

  const int fr = lane & 15;   // A-row / B-row / C-col within 16x16 frag
  const int fq = lane >> 4;   // quad: k-offset fq*8, C-row fq*4
  const u16* Ard = &Als[(((wave >> 1) * 32) + fr) * 32 + fq * 8];
  const u16* Brd = &Bls[(((wave & 1) * 32) + fr) * 32 + fq * 8];

  f32x4 acc[2][2] = {};

  for (int kt = 0; kt < K; kt += 32) {
    async_copy16(gA, &Als[tid * 8]);
    async_copy16(gB, &Bls[tid * 8]);
    gA += 32; gB += 32;
    __syncthreads();   // drains vmcnt -> staged tile visible

    bf16x8 af[2], bfv[2];
#pragma unroll
    for (int i = 0; i < 2; ++i) af[i]  = *(const bf16x8*)(Ard + i * (16 * 32));
#pragma unroll
    for (int j = 0; j < 2; ++j) bfv[j] = *(const bf16x8*)(Brd + j * (16 * 32));
#pragma unroll
    for (int i = 0; i < 2; ++i)
#pragma unroll
      for (int j = 0; j < 2; ++j)
        acc[i][j] = __builtin_amdgcn_mfma_f32_16x16x32_bf16(af[i], bfv[j], acc[i][j], 0, 0, 0);
    __syncthreads();   // before next overwrite
  }

  const long long cb = zo * sCo + zi * sCi;
  const int wr = (wave >> 1) * 32;
  const int wc = (wave & 1) * 32;
#pragma unroll
  for (int i = 0; i < 2; ++i) {
#pragma unroll
    for (int r = 0; r < 4; ++r) {
      const long long row = n0 + wr + i * 16 + fq * 4 + r;
      float rs = 0.f;
      long long crow = row;
      bool ok = true;
      if (OUTMODE == 2) rs = rowscale[row * (long long)rs_stride];
      if (OUTMODE == 3) {
        ok = row < cnt;
        const int tok = ok ? gidx[row] : 0;
        crow = tok;
        rs = ok ? rowscale[(long long)tok * rs_stride] : 0.f;
      }
#pragma unroll
      for (int j = 0; j < 2; ++j) {
        const long long col = m0 + wc + j * 16 + fr;
        float v = acc[i][j][r];
        if (HAS_BIAS) { if (!bias_zi0 || zi == 0) v += bias[col]; }
        if (ACT == 1) v = fmaxf(v, 0.f);
        if (ACT == 2) v = 0.5f * v * (1.f + erff(v * 0.70710678118654752f));
        const long long idx = cb + crow * ldc + col;
        if (OUTMODE == 0)      ((float*)C)[idx] = v;
        else if (OUTMODE == 1) ((u16*)C)[idx] = f2bf(v);
        else if (OUTMODE == 2) ((float*)C)[idx] += rs * v;
        else if (OUTMODE == 3) { if (ok) ((float*)C)[idx] += rs * v; }  // non-atomic scatter
      }
    }
  }
}

template<int ACT, int OUT, int BIAS>
static inline void run_gemm(hipStream_t st,
    const u16* A, const u16* B, void* C, const float* bias,
    const float* rowscale, int rs_stride,
    int N, int M, int K, int lda, int ldb, int ldc,
    int batch, int inner,
    long long sAo, long long sAi, long long sBo, long long sBi,
    long long sCo, long long sCi)
{
  dim3 g(N / 128, M / 128, batch);
  gemm_tile<ACT, OUT, BIAS, 0><<<g, dim3(256), 0, st>>>(
      A, B, C, bias, rowscale, rs_stride, nullptr, nullptr, 0,
      lda, ldb, ldc, K, inner, sAo, sAi, sBo, sBi, sCo, sCi);
}

template<int ACT, int OUT, int BIAS>
static inline void run_gemm64(hipStream_t st,
    const u16* A, const u16* B, void* C, const float* bias,
    const float* rowscale, int rs_stride,
    int N, int M, int K, int lda, int ldb, int ldc,
    int batch, int inner,
    long long sAo, long long sAi, long long sBo, long long sBi,
    long long sCo, long long sCi)
{
  dim3 g(N / 64, M / 64, batch);
  gemm_tile64<ACT, OUT, BIAS, 0><<<g, dim3(256), 0, st>>>(
      A, B, C, bias, rowscale, rs_stride, nullptr, nullptr, 0,
      lda, ldb, ldc, K, inner, sAo, sAi, sBo, sBi, sCo, sCi);
}

// ---------------------------------------------------------------------------
// elementwise / small kernels
// ---------------------------------------------------------------------------
__global__ void cast_bf16_k(const float* __restrict__ s, u16* __restrict__ d, long long n)
{
  long long i = (long long)blockIdx.x * blockDim.x + threadIdx.x;
  const long long stride = (long long)gridDim.x * blockDim.x;
  for (; i < n; i += stride) d[i] = f2bf(s[i]);
}

__global__ void transpose_f32_k(const float* __restrict__ s, float* __restrict__ d,
                                int rows, int cols)
{
  int i = blockIdx.x * blockDim.x + threadIdx.x;
  if (i < rows * cols) { int r = i / cols, c = i - r * cols; d[c * rows + r] = s[i]; }
}

// patch gather + relu(t@w1T)+relu(.@w2T) + sinusoidal PE -> z bf16 [16384,128]
__global__ __launch_bounds__(64)
void tokenizer_k(const float* __restrict__ x, const float* __restrict__ w1T,
                 const float* __restrict__ b1, const float* __restrict__ w2T,
                 const float* __restrict__ b2, u16* __restrict__ z)
{
  const int token = blockIdx.x;             // b*1024 + s
  const int b = token >> 10, s = token & 1023;
  const int ph = s >> 5, pw = s & 31;
  const int lane = threadIdx.x;
  __shared__ float t[320];
  __shared__ float z1[64];
  const int py = lane >> 3, px = lane & 7;
  const float* xp = x + (size_t)b * 5 * 65536 + (size_t)(ph * 8 + py) * 256 + pw * 8 + px;
#pragma unroll
  for (int c = 0; c < 5; ++c) t[c * 64 + lane] = xp[(size_t)c * 65536];
  __syncthreads();
  float acc = b1[lane];
  for (int k = 0; k < 320; ++k) acc = fmaf(t[k], w1T[k * 64 + lane], acc);
  z1[lane] = fmaxf(acc, 0.f);
  __syncthreads();
  float a0 = b2[lane], a1 = b2[lane + 64];
  for (int k = 0; k < 64; ++k) {
    const float zv = z1[k];
    a0 = fmaf(zv, w2T[k * 128 + lane], a0);
    a1 = fmaf(zv, w2T[k * 128 + lane + 64], a1);
  }
  a0 = fmaxf(a0, 0.f); a1 = fmaxf(a1, 0.f);
  const float fs = (float)s;
  const int d0 = lane, d1 = lane + 64;
  const float div0 = expf(-logf(10000.f) * (float)(d0 & ~1) / 128.f);
  const float div1 = expf(-logf(10000.f) * (float)(d1 & ~1) / 128.f);
  const float pe0 = (d0 & 1) ? cosf(fs * div0) : sinf(fs * div0);
  const float pe1 = (d1 & 1) ? cosf(fs * div1) : sinf(fs * div1);
  z[(size_t)token * 128 + d0] = f2bf(a0 + pe0);
  z[(size_t)token * 128 + d1] = f2bf(a1 + pe1);
}

// V slice of qkv -> vT[z=b*4+h][d][s], LDS-tiled transpose
__global__ void transpose_v_k(const u16* __restrict__ qkv, u16* __restrict__ vT)
{
  __shared__ u16 tile[32][33];
  const int z = blockIdx.z;
  const int b = z >> 2, hh = z & 3;
  const int s0 = blockIdx.x * 32, d0 = blockIdx.y * 32;
  const int tx = threadIdx.x;
  for (int i = threadIdx.y; i < 32; i += 8)
    tile[i][tx] = qkv[(long long)(b * 1024 + s0 + i) * 1536 + 1024 + hh * 128 + d0 + tx];
  __syncthreads();
  for (int j = threadIdx.y; j < 32; j += 8)
    vT[((long long)z * 128 + d0 + j) * 1024 + s0 + tx] = tile[tx][j];
}

// in-place row softmax (1024 cols, bf16), applies scale before softmax
__global__ __launch_bounds__(256)
void softmax_k(u16* __restrict__ P, float scale)
{
  const long long row = blockIdx.x;
  u16* p = P + row * 1024;
  const int tid = threadIdx.x;
  float v[4];
#pragma unroll
  for (int j = 0; j < 4; ++j) v[j] = bf2f(p[tid + j * 256]) * scale;
  __shared__ float red[256];
  float mx = fmaxf(fmaxf(v[0], v[1]), fmaxf(v[2], v[3]));
  red[tid] = mx; __syncthreads();
  for (int s = 128; s > 0; s >>= 1) { if (tid < s) red[tid] = fmaxf(red[tid], red[tid + s]); __syncthreads(); }
  mx = red[0]; __syncthreads();
  float sum = 0.f;
#pragma unroll
  for (int j = 0; j < 4; ++j) { v[j] = expf(v[j] - mx); sum += v[j]; }
  red[tid] = sum; __syncthreads();
  for (int s = 128; s > 0; s >>= 1) { if (tid < s) red[tid] += red[tid + s]; __syncthreads(); }
  const float inv = 1.f / red[0];
#pragma unroll
  for (int j = 0; j < 4; ++j) p[tid + j * 256] = f2bf(v[j] * inv);
}

// h = LN(h + a); writes h fp32 and bf16 copy
__global__ __launch_bounds__(256)
void ln_add_k(float* __restrict__ h, const float* __restrict__ a,
              const float* __restrict__ g, const float* __restrict__ b,
              u16* __restrict__ hbf)
{
  const long long t = blockIdx.x;
  const int tid = threadIdx.x;
  float* hp = h + t * 512;
  const float* ap = a + t * 512;
  const float x0 = hp[tid] + ap[tid];
  const float x1 = hp[tid + 256] + ap[tid + 256];
  __shared__ float r1[256], r2[256];
  r1[tid] = x0 + x1; r2[tid] = x0 * x0 + x1 * x1;
  __syncthreads();
  for (int s = 128; s > 0; s >>= 1) { if (tid < s) { r1[tid] += r1[tid + s]; r2[tid] += r2[tid + s]; } __syncthreads(); }
  const float mean = r1[0] * (1.f / 512.f);
  const float var  = r2[0] * (1.f / 512.f) - mean * mean;
  const float rstd = rsqrtf(var + 1e-5f);
  const float y0 = (x0 - mean) * rstd * g[tid] + b[tid];
  const float y1 = (x1 - mean) * rstd * g[tid + 256] + b[tid + 256];
  hp[tid] = y0; hp[tid + 256] = y1;
  hbf[t * 512 + tid] = f2bf(y0); hbf[t * 512 + tid + 256] = f2bf(y1);
}

// m = LN(h+macc, g1,b1); h = LN(h+m, g2,b2); writes h fp32 + bf16
__global__ __launch_bounds__(256)
void merge_ln_k(float* __restrict__ h, const float* __restrict__ macc,
                const float* __restrict__ g1, const float* __restrict__ b1,
                const float* __restrict__ g2, const float* __restrict__ b2,
                u16* __restrict__ hbf)
{
  const long long t = blockIdx.x;
  const int tid = threadIdx.x;
  float* hp = h + t * 512;
  const float* mp = macc + t * 512;
  const float hx0 = hp[tid], hx1 = hp[tid + 256];
  const float s0 = hx0 + mp[tid], s1 = hx1 + mp[tid + 256];
  __shared__ float r1[256], r2[256];
  r1[tid] = s0 + s1; r2[tid] = s0 * s0 + s1 * s1;
  __syncthreads();
  for (int s = 128; s > 0; s >>= 1) { if (tid < s) { r1[tid] += r1[tid + s]; r2[tid] += r2[tid + s]; } __syncthreads(); }
  float mean = r1[0] * (1.f / 512.f);
  float var  = r2[0] * (1.f / 512.f) - mean * mean;
  float rstd = rsqrtf(var + 1e-5f);
  const float m0v = (s0 - mean) * rstd * g1[tid] + b1[tid];
  const float m1v = (s1 - mean) * rstd * g1[tid + 256] + b1[tid + 256];
  const float z0 = hx0 + m0v, z1 = hx1 + m1v;
  __syncthreads();
  r1[tid] = z0 + z1; r2[tid] = z0 * z0 + z1 * z1;
  __syncthreads();
  for (int s = 128; s > 0; s >>= 1) { if (tid < s) { r1[tid] += r1[tid + s]; r2[tid] += r2[tid + s]; } __syncthreads(); }
  mean = r1[0] * (1.f / 512.f);
  var  = r2[0] * (1.f / 512.f) - mean * mean;
  rstd = rsqrtf(var + 1e-5f);
  const float y0 = (z0 - mean) * rstd * g2[tid] + b2[tid];
  const float y1 = (z1 - mean) * rstd * g2[tid + 256] + b2[tid + 256];
  hp[tid] = y0; hp[tid + 256] = y1;
  hbf[t * 512 + tid] = f2bf(y0); hbf[t * 512 + tid + 256] = f2bf(y1);
}

// per-token: spec router softmax + top2-normalized comb[6]; shared softmax sp[2]
__global__ __launch_bounds__(64)
void router_k(const float* __restrict__ h, const float* __restrict__ sw,
              const float* __restrict__ hw, float* __restrict__ comb,
              float* __restrict__ sp)
{
  const long long t = blockIdx.x;
  const int lane = threadIdx.x;
  const float* hp = h + t * 512;
  float v[8];
#pragma unroll
  for (int j = 0; j < 8; ++j) v[j] = hp[lane + j * 64];

  float lg[6];
#pragma unroll
  for (int e = 0; e < 6; ++e) {
    const float* w = sw + e * 512;
    float d = 0.f;
#pragma unroll
    for (int j = 0; j < 8; ++j) d += v[j] * w[lane + j * 64];
#pragma unroll
    for (int off = 32; off > 0; off >>= 1) d += __shfl_xor(d, off);
    lg[e] = d;
  }
  float mx = lg[0];
#pragma unroll
  for (int e = 1; e < 6; ++e) mx = fmaxf(mx, lg[e]);
  float pp[6]; float sum = 0.f;
#pragma unroll
  for (int e = 0; e < 6; ++e) { pp[e] = expf(lg[e] - mx); sum += pp[e]; }
  const float inv = 1.f / sum;
#pragma unroll
  for (int e = 0; e < 6; ++e) pp[e] *= inv;

  int i1 = 0; float p1 = pp[0];
#pragma unroll
  for (int e = 1; e < 6; ++e) if (pp[e] > p1) { p1 = pp[e]; i1 = e; }   // ties -> lower idx
  int i2 = -1; float p2 = -1.f;
#pragma unroll
  for (int e = 0; e < 6; ++e) if (e != i1 && pp[e] > p2) { p2 = pp[e]; i2 = e; }
  const float den = 1.f / (p1 + p2 + 1e-9f);
  if (lane == 0) {
#pragma unroll
    for (int e = 0; e < 6; ++e)
      comb[t * 6 + e] = (e == i1) ? p1 * den : ((e == i2) ? p2 * den : 0.f);
  }

  float l0 = 0.f, l1 = 0.f;
#pragma unroll
  for (int j = 0; j < 8; ++j) {
    l0 += v[j] * hw[lane + j * 64];
    l1 += v[j] * hw[512 + lane + j * 64];
  }
#pragma unroll
  for (int off = 32; off > 0; off >>= 1) { l0 += __shfl_xor(l0, off); l1 += __shfl_xor(l1, off); }
  const float m2 = fmaxf(l0, l1);
  const float e0 = expf(l0 - m2), e1 = expf(l1 - m2);
  const float si = 1.f / (e0 + e1);
  if (lane == 0) { sp[t * 2 + 0] = e0 * si; sp[t * 2 + 1] = e1 * si; }
}

// per-expert token lists from comb (order within an expert is irrelevant)
__global__ __launch_bounds__(256)
void build_lists_k(const float* __restrict__ comb, int* __restrict__ cnt,
                   int* __restrict__ idx)
{
  const int t = blockIdx.x * blockDim.x + threadIdx.x;
  if (t >= 16384) return;
#pragma unroll
  for (int e = 0; e < 6; ++e) {
    if (comb[(long long)t * 6 + e] > 0.f) {
      const int pos = atomicAdd(&cnt[e], 1);
      idx[e * 16384 + pos] = t;
    }
  }
}

// mean over S then logits = pooled @ cls_w.T + cls_b
__global__ __launch_bounds__(256)
void pool_cls_k(const float* __restrict__ h, const float* __restrict__ cw,
                const float* __restrict__ cb, float* __restrict__ out)
{
  const int b = blockIdx.x;
  const int tid = threadIdx.x;
  const float* hp = h + (size_t)b * 1024 * 512;
  float s0 = 0.f, s1 = 0.f;
  for (int s = 0; s < 1024; ++s) {
    s0 += hp[(size_t)s * 512 + tid];
    s1 += hp[(size_t)s * 512 + tid + 256];
  }
  __shared__ float pooled[512];
  pooled[tid] = s0 * (1.f / 1024.f); pooled[tid + 256] = s1 * (1.f / 1024.f);
  __syncthreads();
  __shared__ float red[256];
  for (int c = 0; c < 2; ++c) {
    const float d = pooled[tid] * cw[c * 512 + tid] + pooled[tid + 256] * cw[c * 512 + tid + 256];
    red[tid] = d; __syncthreads();
    for (int s = 128; s > 0; s >>= 1) { if (tid < s) red[tid] += red[tid + s]; __syncthreads(); }
    if (tid == 0) out[b * 2 + c] = red[0] + cb[c];
    __syncthreads();
  }
}

// ---------------------------------------------------------------------------
extern "C" void kernel_launch(void* const* d_in, const int* in_sizes, int n_in,
                              void* d_out, int out_size, void* d_ws, size_t ws_size,
                              hipStream_t stream)
{
  (void)in_sizes; (void)n_in; (void)out_size; (void)ws_size;
  const float* x      = (const float*)d_in[0];
  const float* tok_w1 = (const float*)d_in[1];
  const float* tok_b1 = (const float*)d_in[2];
  const float* tok_w2 = (const float*)d_in[3];
  const float* tok_b2 = (const float*)d_in[4];
  const float* proj_w = (const float*)d_in[5];
  const float* proj_b = (const float*)d_in[6];
  const float* wqkv   = (const float*)d_in[7];
  const float* bqkv   = (const float*)d_in[8];
  const float* wo     = (const float*)d_in[9];
  const float* bo     = (const float*)d_in[10];
  const float* ln1_g  = (const float*)d_in[11];
  const float* ln1_b  = (const float*)d_in[12];
  const float* srw    = (const float*)d_in[13];
  const float* sfc1w  = (const float*)d_in[14];
  const float* sfc1b  = (const float*)d_in[15];
  const float* sfc2w  = (const float*)d_in[16];
  const float* sfc2b  = (const float*)d_in[17];
  const float* hrw    = (const float*)d_in[18];
  const float* hfc1w  = (const float*)d_in[19];
  const float* hfc1b  = (const float*)d_in[20];
  const float* hfc2w  = (const float*)d_in[21];
  const float* hfc2b  = (const float*)d_in[22];
  const float* lnm_g  = (const float*)d_in[23];
  const float* lnm_b  = (const float*)d_in[24];
  const float* ln2_g  = (const float*)d_in[25];
  const float* ln2_b  = (const float*)d_in[26];
  const float* cls_w  = (const float*)d_in[27];
  const float* cls_b  = (const float*)d_in[28];

  char* ws = (char*)d_ws;
  size_t off = 0;
  auto alloc = [&](size_t bytes) -> char* {
    char* p = ws + off;
    off = (off + bytes + 255) & ~(size_t)255;
    return p;
  };

  // bf16 weight copies (re-created every call; inputs restored each launch)
  u16* proj_bf = (u16*)alloc((size_t)512 * 128 * 2);
  u16* qkvw_bf = (u16*)alloc((size_t)4 * 1536 * 512 * 2);
  u16* wow_bf  = (u16*)alloc((size_t)4 * 512 * 512 * 2);
  u16* sfc1_bf = (u16*)alloc((size_t)4 * 6 * 2048 * 512 * 2);
  u16* sfc2_bf = (u16*)alloc((size_t)4 * 6 * 512 * 2048 * 2);
  u16* hfc1_bf = (u16*)alloc((size_t)4 * 2 * 2048 * 512 * 2);
  u16* hfc2_bf = (u16*)alloc((size_t)4 * 2 * 512 * 2048 * 2);
  float* w1T   = (float*)alloc((size_t)320 * 64 * 4);
  float* w2T   = (float*)alloc((size_t)64 * 128 * 4);
  u16* zbf     = (u16*)alloc((size_t)16384 * 128 * 2);
  float* h     = (float*)alloc((size_t)16384 * 512 * 4);
  u16* hbf     = (u16*)alloc((size_t)16384 * 512 * 2);
  u16* vT      = (u16*)alloc((size_t)64 * 128 * 1024 * 2);
  u16* abf     = (u16*)alloc((size_t)16384 * 512 * 2);
  int* cnt     = (int*)alloc((size_t)6 * 4);
  int* idx     = (int*)alloc((size_t)6 * 16384 * 4);
  // regionA (67MB): scores chunk (32 bh x 1024 x 1024 bf16) / wo-out fp32 / hid bf16
  char* regA   = alloc((size_t)32 * 1024 * 1024 * 2);
  // regionB (50MB): qkv bf16 [16384,1536] / (moe_acc fp32 + comb + sp)
  char* regB   = alloc((size_t)16384 * 1536 * 2);
  u16*   scores = (u16*)regA;
  float* af32   = (float*)regA;
  u16*   hid    = (u16*)regA;
  u16*   qkv    = (u16*)regB;
  float* macc   = (float*)regB;
  float* comb   = (float*)(regB + (size_t)16384 * 512 * 4);
  float* sp     = (float*)(regB + (size_t)16384 * 512 * 4 + (size_t)16384 * 6 * 4);

  // ---- weight prep ----
  cast_bf16_k<<<4096, 256, 0, stream>>>(proj_w, proj_bf, 65536LL);
  cast_bf16_k<<<4096, 256, 0, stream>>>(wqkv,   qkvw_bf, 3145728LL);
  cast_bf16_k<<<4096, 256, 0, stream>>>(wo,     wow_bf,  1048576LL);
  cast_bf16_k<<<4096, 256, 0, stream>>>(sfc1w,  sfc1_bf, 25165824LL);
  cast_bf16_k<<<4096, 256, 0, stream>>>(sfc2w,  sfc2_bf, 25165824LL);
  cast_bf16_k<<<4096, 256, 0, stream>>>(hfc1w,  hfc1_bf, 8388608LL);
  cast_bf16_k<<<4096, 256, 0, stream>>>(hfc2w,  hfc2_bf, 8388608LL);
  transpose_f32_k<<<(20480 + 255) / 256, 256, 0, stream>>>(tok_w1, w1T, 64, 320);
  transpose_f32_k<<<(8192 + 255) / 256, 256, 0, stream>>>(tok_w2, w2T, 128, 64);

  // ---- tokenizer + PE -> z, proj -> h ----
  tokenizer_k<<<16384, 64, 0, stream>>>(x, w1T, tok_b1, w2T, tok_b2, zbf);
  run_gemm64<0, 0, 1>(stream, zbf, proj_bf, h, proj_b, nullptr, 0,
                      16384, 512, 128, 128, 128, 512, 1, 1, 0, 0, 0, 0, 0, 0);
  cast_bf16_k<<<4096, 256, 0, stream>>>(h, hbf, 8388608LL);

  for (int l = 0; l < 4; ++l) {
    // qkv (wide M -> 128^2 tile is fine: 1536 blocks)
    run_gemm<0, 1, 1>(stream, hbf, qkvw_bf + (size_t)l * 1536 * 512, qkv,
                      bqkv + l * 1536, nullptr, 0,
                      16384, 1536, 512, 512, 512, 1536, 1, 1, 0, 0, 0, 0, 0, 0);
    transpose_v_k<<<dim3(32, 4, 64), dim3(32, 8), 0, stream>>>(qkv, vT);
    // attention in 2 half-batch chunks (caps score buffer at 67MB)
    for (int c = 0; c < 2; ++c) {
      const u16* qb = qkv + (size_t)c * 8 * 1024 * 1536;
      run_gemm<0, 1, 0>(stream, qb, qb + 512, scores, nullptr, nullptr, 0,
                        1024, 1024, 128, 1536, 1536, 1024, 32, 4,
                        1024LL * 1536, 128, 1024LL * 1536, 128,
                        4LL * 1024 * 1024, 1024LL * 1024);
      softmax_k<<<32768, 256, 0, stream>>>(scores, 0.08838834764831845f);
      // PV is skinny (M=128): 64^2 tile -> grid (16,2,32)=1024 blocks
      run_gemm64<0, 1, 0>(stream, scores, vT + (size_t)c * 8 * 4 * 128 * 1024,
                          abf + (size_t)c * 8 * 1024 * 512, nullptr, nullptr, 0,
                          1024, 128, 1024, 1024, 1024, 512, 32, 4,
                          4LL * 1024 * 1024, 1024LL * 1024,
                          4LL * 128 * 1024, 128LL * 1024,
                          1024LL * 512, 128);
    }
    // output projection (skinny M=512): 64^2 tile -> 2048 blocks
    run_gemm64<0, 0, 1>(stream, abf, wow_bf + (size_t)l * 512 * 512, af32,
                        bo + l * 512, nullptr, 0,
                        16384, 512, 512, 512, 512, 512, 1, 1, 0, 0, 0, 0, 0, 0);
    hipMemsetAsync(macc, 0, (size_t)16384 * 512 * 4, stream);  // qkv dead now
    ln_add_k<<<16384, 256, 0, stream>>>(h, af32, ln1_g + l * 512, ln1_b + l * 512, hbf);
    router_k<<<16384, 64, 0, stream>>>(h, srw + (size_t)l * 6 * 512,
                                       hrw + (size_t)l * 2 * 512, comb, sp);
    hipMemsetAsync(cnt, 0, 6 * sizeof(int), stream);
    build_lists_k<<<64, 256, 0, stream>>>(comb, cnt, idx);
    // specific experts: sparse (top-2), gathered rows; identical math to ref
    for (int e = 0; e < 6; ++e) {
      const size_t wi = (size_t)(l * 6 + e);
      // fc1: gather A rows by token list, gelu, bf16 store (position space); 64^2 tile
      gemm_tile64<2, 1, 1, 1><<<dim3(256, 32, 1), dim3(256), 0, stream>>>(
          hbf, sfc1_bf + wi * 2048 * 512, hid,
          sfc1b + wi * 2048, nullptr, 0, idx + e * 16384, cnt + e, 0,
          512, 512, 2048, 512, 1, 0, 0, 0, 0, 0, 0);
      // fc2: 64^2 tile, z=1, NON-atomic scatter += (rows unique within dispatch)
      gemm_tile64<0, 3, 1, 0><<<dim3(256, 8, 1), dim3(256), 0, stream>>>(
          hid, sfc2_bf + wi * 512 * 2048, macc,
          sfc2b + wi * 512, comb + e, 6, idx + e * 16384, cnt + e, 0,
          2048, 2048, 512, 2048, 1, 0, 0, 0, 0, 0, 0);
    }
    // shared experts (dense): fc1 on 128^2 (2048 blocks); fc2 skinny -> 64^2 dense +=
    for (int e = 0; e < 2; ++e) {
      const size_t wi = (size_t)(l * 2 + e);
      run_gemm<2, 1, 1>(stream, hbf, hfc1_bf + wi * 2048 * 512, hid,
                        hfc1b + wi * 2048, nullptr, 0,
                        16384, 2048, 512, 512, 512, 2048, 1, 1, 0, 0, 0, 0, 0, 0);
      run_gemm64<0, 2, 1>(stream, hid, hfc2_bf + wi * 512 * 2048, macc,
                          hfc2b + wi * 512, sp + e, 2,
                          16384, 512, 2048, 2048, 2048, 512, 1, 1, 0, 0, 0, 0, 0, 0);
    }
    merge_ln_k<<<16384, 256, 0, stream>>>(h, macc, lnm_g + l * 512, lnm_b + l * 512,
                                          ln2_g + l * 512, ln2_b + l * 512, hbf);
  }

  pool_cls_k<<<16, 256, 0, stream>>>(h, cls_w, cls_b, (float*)d_out);
}

// Round 5
// 5719.423 us; speedup vs baseline: 1.2665x; 1.0840x over previous
//
#include <hip/hip_runtime.h>

typedef unsigned short u16;
using bf16x8 = __attribute__((ext_vector_type(8))) short;
using f32x4  = __attribute__((ext_vector_type(4))) float;
using u16x4  = __attribute__((ext_vector_type(4))) unsigned short;

__device__ __forceinline__ float bf2f(u16 u) {
  union { unsigned int i; float f; } v; v.i = ((unsigned int)u) << 16; return v.f;
}
__device__ __forceinline__ u16 f2bf(float f) {
  union { float f; unsigned int i; } v; v.f = f;
  unsigned int r = v.i + 0x7fffu + ((v.i >> 16) & 1u);  // RNE
  return (u16)(r >> 16);
}

// async global->LDS, 16B per lane. LDS side must be wave-uniform base + lane*16.
__device__ __forceinline__ void async_copy16(const u16* g, u16* l) {
  __builtin_amdgcn_global_load_lds(
      (const __attribute__((address_space(1))) void*)g,
      (__attribute__((address_space(3))) void*)l, 16, 0, 0);
}

// ---------------------------------------------------------------------------
// m97-style bf16 GEMM: C[N,M] = A[N,K] * B[M,K]^T  (B given row-major [M,K])
// 128x128 tile, BK=32, 4 waves each computing 64x64 via 4x4 of 16x16x32 MFMA.
// Batched via blockIdx.z with two-level (outer,inner) strides.
// OUTMODE: 0 = fp32 store, 1 = bf16 store, 2 = fp32 C += rowscale[row]*val,
//          3 = scatter: C[gidx[row]*ldc+col] += rowscale[gidx[row]]*val (atomic), guarded by *gcnt
// GA: gather A rows through gidx (count-guarded; padded rows use token 0)
// ACT: 0 none, 1 relu, 2 exact gelu.  All dims must be multiples of tile.
// Epilogue uses int32 row*ldc (all C buffers < 2^31 elems) + immediate-offset
// stores (cp[j*16]) -- the 64-bit per-element address math was 46% VALUBusy.
// ---------------------------------------------------------------------------
template<int ACT, int OUTMODE, int HAS_BIAS, int GA>
__global__ __launch_bounds__(256)
void gemm_tile(const u16* __restrict__ A, const u16* __restrict__ B,
               void* __restrict__ C,
               const float* __restrict__ bias,
               const float* __restrict__ rowscale, int rs_stride,
               const int* __restrict__ gidx, const int* __restrict__ gcnt,
               int bias_zi0,
               int lda, int ldb, int ldc, int K, int inner,
               long long sAo, long long sAi, long long sBo, long long sBi,
               long long sCo, long long sCi)
{
  __shared__ u16 Als[128 * 32];
  __shared__ u16 Bls[128 * 32];

  const int tid  = threadIdx.x;
  const int lane = tid & 63;
  const int wave = tid >> 6;

  const int z  = blockIdx.z;
  const int zo = z / inner;
  const int zi = z - zo * inner;

  const long long n0 = (long long)blockIdx.x * 128;
  const long long m0 = (long long)blockIdx.y * 128;

  int cnt = 0x7fffffff;
  if (GA || OUTMODE == 3) {
    cnt = *gcnt;
    if (n0 >= cnt) return;      // uniform early exit for padded grid
  }

  const u16* Ab = A + zo * sAo + zi * sAi;
  const u16* Bb = B + zo * sBo + zi * sBi;

  // staging: 512 16B-chunks per tile; thread handles chunks tid and tid+256
  const int c0 = tid, c1 = tid + 256;
  const int rA0 = c0 >> 2, kA0 = (c0 & 3) * 8;
  const int rA1 = c1 >> 2, kA1 = (c1 & 3) * 8;

  long long arow0 = n0 + rA0, arow1 = n0 + rA1;
  if (GA) {
    arow0 = (arow0 < cnt) ? (long long)gidx[arow0] : 0;
    arow1 = (arow1 < cnt) ? (long long)gidx[arow1] : 0;
  }
  const u16* gA0 = Ab + arow0 * lda + kA0;
  const u16* gA1 = Ab + arow1 * lda + kA1;
  const u16* gB0 = Bb + (m0 + rA0) * ldb + kA0;
  const u16* gB1 = Bb + (m0 + rA1) * ldb + kA1;

  const int fr = lane & 15;   // A-row / B-row / C-col within 16x16 frag
  const int fq = lane >> 4;   // quad: k-offset fq*8, C-row fq*4
  const u16* Ard = &Als[(((wave >> 1) * 64) + fr) * 32 + fq * 8];
  const u16* Brd = &Bls[(((wave & 1) * 64) + fr) * 32 + fq * 8];

  f32x4 acc[4][4] = {};

  for (int kt = 0; kt < K; kt += 32) {
    async_copy16(gA0, &Als[c0 * 8]);
    async_copy16(gA1, &Als[c1 * 8]);
    async_copy16(gB0, &Bls[c0 * 8]);
    async_copy16(gB1, &Bls[c1 * 8]);
    gA0 += 32; gA1 += 32; gB0 += 32; gB1 += 32;
    __syncthreads();   // drains vmcnt -> staged tile visible

    bf16x8 af[4], bfv[4];
#pragma unroll
    for (int i = 0; i < 4; ++i) af[i]  = *(const bf16x8*)(Ard + i * (16 * 32));
#pragma unroll
    for (int j = 0; j < 4; ++j) bfv[j] = *(const bf16x8*)(Brd + j * (16 * 32));
#pragma unroll
    for (int i = 0; i < 4; ++i)
#pragma unroll
      for (int j = 0; j < 4; ++j)
        acc[i][j] = __builtin_amdgcn_mfma_f32_16x16x32_bf16(af[i], bfv[j], acc[i][j], 0, 0, 0);
    __syncthreads();   // before next overwrite
  }

  const long long cb = zo * sCo + zi * sCi;
  const int wr = (wave >> 1) * 64;
  const int wc = (wave & 1) * 64;
  const int colbase = (int)m0 + wc + fr;   // per-thread fixed column base

  float bv[4] = {0.f, 0.f, 0.f, 0.f};
  if (HAS_BIAS) {
    if (!bias_zi0 || zi == 0) {
#pragma unroll
      for (int j = 0; j < 4; ++j) bv[j] = bias[colbase + j * 16];
    }
  }

#pragma unroll
  for (int i = 0; i < 4; ++i) {
#pragma unroll
    for (int r = 0; r < 4; ++r) {
      const int row = (int)n0 + wr + i * 16 + fq * 4 + r;
      float rs = 0.f;
      int crow = row;
      bool ok = true;
      if (OUTMODE == 2) rs = rowscale[row * rs_stride];
      if (OUTMODE == 3) {
        ok = row < cnt;
        const int tok = ok ? gidx[row] : 0;
        crow = tok;
        rs = ok ? rowscale[tok * rs_stride] : 0.f;
      }
      // int32 within-slice offset (fits: all C slices < 2^31 elements)
      const long long base = cb + (long long)(crow * ldc + colbase);
      float* __restrict__ cf = (float*)C + base;
      u16*   __restrict__ ch = (u16*)C + base;
#pragma unroll
      for (int j = 0; j < 4; ++j) {
        float v = acc[i][j][r];
        if (HAS_BIAS) v += bv[j];
        if (ACT == 1) v = fmaxf(v, 0.f);
        if (ACT == 2) v = 0.5f * v * (1.f + erff(v * 0.70710678118654752f));
        if (OUTMODE == 0)      cf[j * 16] = v;
        else if (OUTMODE == 1) ch[j * 16] = f2bf(v);
        else if (OUTMODE == 2) cf[j * 16] += rs * v;
        else if (ok)           atomicAdd(&cf[j * 16], rs * v);
      }
    }
  }
}

// ---------------------------------------------------------------------------
// 64x64-tile variant for skinny / low-grid GEMMs (4x the blocks of 128x128).
// 4 waves each compute a 32x32 quadrant via 2x2 of 16x16x32 MFMA. 8KB LDS.
// OUTMODE 3 here is a NON-atomic scatter += (rows unique within a dispatch;
// different experts are sequential dispatches on the same stream).
// ---------------------------------------------------------------------------
template<int ACT, int OUTMODE, int HAS_BIAS, int GA>
__global__ __launch_bounds__(256)
void gemm_tile64(const u16* __restrict__ A, const u16* __restrict__ B,
                 void* __restrict__ C,
                 const float* __restrict__ bias,
                 const float* __restrict__ rowscale, int rs_stride,
                 const int* __restrict__ gidx, const int* __restrict__ gcnt,
                 int bias_zi0,
                 int lda, int ldb, int ldc, int K, int inner,
                 long long sAo, long long sAi, long long sBo, long long sBi,
                 long long sCo, long long sCi)
{
  __shared__ u16 Als[64 * 32];
  __shared__ u16 Bls[64 * 32];

  const int tid  = threadIdx.x;
  const int lane = tid & 63;
  const int wave = tid >> 6;

  const int z  = blockIdx.z;
  const int zo = z / inner;
  const int zi = z - zo * inner;

  const long long n0 = (long long)blockIdx.x * 64;
  const long long m0 = (long long)blockIdx.y * 64;

  int cnt = 0x7fffffff;
  if (GA || OUTMODE == 3) {
    cnt = *gcnt;
    if (n0 >= cnt) return;      // uniform early exit for padded grid
  }

  const u16* Ab = A + zo * sAo + zi * sAi;
  const u16* Bb = B + zo * sBo + zi * sBi;

  // staging: 256 16B-chunks per tile; thread tid handles A chunk tid and B chunk tid
  const int rA = tid >> 2, kA = (tid & 3) * 8;

  long long arow = n0 + rA;
  if (GA) arow = (arow < cnt) ? (long long)gidx[arow] : 0;
  const u16* gA = Ab + arow * lda + kA;
  const u16* gB = Bb + (m0 + rA) * ldb + kA;

  const int fr = lane & 15;   // A-row / B-row / C-col within 16x16 frag
  const int fq = lane >> 4;   // quad: k-offset fq*8, C-row fq*4
  const u16* Ard = &Als[(((wave >> 1) * 32) + fr) * 32 + fq * 8];
  const u16* Brd = &Bls[(((wave & 1) * 32) + fr) * 32 + fq * 8];

  f32x4 acc[2][2] = {};

  for (int kt = 0; kt < K; kt += 32) {
    async_copy16(gA, &Als[tid * 8]);
    async_copy16(gB, &Bls[tid * 8]);
    gA += 32; gB += 32;
    __syncthreads();   // drains vmcnt -> staged tile visible

    bf16x8 af[2], bfv[2];
#pragma unroll
    for (int i = 0; i < 2; ++i) af[i]  = *(const bf16x8*)(Ard + i * (16 * 32));
#pragma unroll
    for (int j = 0; j < 2; ++j) bfv[j] = *(const bf16x8*)(Brd + j * (16 * 32));
#pragma unroll
    for (int i = 0; i < 2; ++i)
#pragma unroll
      for (int j = 0; j < 2; ++j)
        acc[i][j] = __builtin_amdgcn_mfma_f32_16x16x32_bf16(af[i], bfv[j], acc[i][j], 0, 0, 0);
    __syncthreads();   // before next overwrite
  }

  const long long cb = zo * sCo + zi * sCi;
  const int wr = (wave >> 1) * 32;
  const int wc = (wave & 1) * 32;
  const int colbase = (int)m0 + wc + fr;

  float bv[2] = {0.f, 0.f};
  if (HAS_BIAS) {
    if (!bias_zi0 || zi == 0) {
#pragma unroll
      for (int j = 0; j < 2; ++j) bv[j] = bias[colbase + j * 16];
    }
  }

#pragma unroll
  for (int i = 0; i < 2; ++i) {
#pragma unroll
    for (int r = 0; r < 4; ++r) {
      const int row = (int)n0 + wr + i * 16 + fq * 4 + r;
      float rs = 0.f;
      int crow = row;
      bool ok = true;
      if (OUTMODE == 2) rs = rowscale[row * rs_stride];
      if (OUTMODE == 3) {
        ok = row < cnt;
        const int tok = ok ? gidx[row] : 0;
        crow = tok;
        rs = ok ? rowscale[tok * rs_stride] : 0.f;
      }
      const long long base = cb + (long long)(crow * ldc + colbase);
      float* __restrict__ cf = (float*)C + base;
      u16*   __restrict__ ch = (u16*)C + base;
#pragma unroll
      for (int j = 0; j < 2; ++j) {
        float v = acc[i][j][r];
        if (HAS_BIAS) v += bv[j];
        if (ACT == 1) v = fmaxf(v, 0.f);
        if (ACT == 2) v = 0.5f * v * (1.f + erff(v * 0.70710678118654752f));
        if (OUTMODE == 0)      cf[j * 16] = v;
        else if (OUTMODE == 1) ch[j * 16] = f2bf(v);
        else if (OUTMODE == 2) cf[j * 16] += rs * v;
        else if (OUTMODE == 3) { if (ok) cf[j * 16] += rs * v; }  // non-atomic scatter
      }
    }
  }
}

template<int ACT, int OUT, int BIAS>
static inline void run_gemm(hipStream_t st,
    const u16* A, const u16* B, void* C, const float* bias,
    const float* rowscale, int rs_stride,
    int N, int M, int K, int lda, int ldb, int ldc,
    int batch, int inner,
    long long sAo, long long sAi, long long sBo, long long sBi,
    long long sCo, long long sCi)
{
  dim3 g(N / 128, M / 128, batch);
  gemm_tile<ACT, OUT, BIAS, 0><<<g, dim3(256), 0, st>>>(
      A, B, C, bias, rowscale, rs_stride, nullptr, nullptr, 0,
      lda, ldb, ldc, K, inner, sAo, sAi, sBo, sBi, sCo, sCi);
}

template<int ACT, int OUT, int BIAS>
static inline void run_gemm64(hipStream_t st,
    const u16* A, const u16* B, void* C, const float* bias,
    const float* rowscale, int rs_stride,
    int N, int M, int K, int lda, int ldb, int ldc,
    int batch, int inner,
    long long sAo, long long sAi, long long sBo, long long sBi,
    long long sCo, long long sCi)
{
  dim3 g(N / 64, M / 64, batch);
  gemm_tile64<ACT, OUT, BIAS, 0><<<g, dim3(256), 0, st>>>(
      A, B, C, bias, rowscale, rs_stride, nullptr, nullptr, 0,
      lda, ldb, ldc, K, inner, sAo, sAi, sBo, sBi, sCo, sCi);
}

// ---------------------------------------------------------------------------
// elementwise / small kernels
// ---------------------------------------------------------------------------
__global__ void cast_bf16_k(const float* __restrict__ s, u16* __restrict__ d, long long n)
{
  long long i = (long long)blockIdx.x * blockDim.x + threadIdx.x;
  const long long stride = (long long)gridDim.x * blockDim.x;
  for (; i < n; i += stride) d[i] = f2bf(s[i]);
}

__global__ void transpose_f32_k(const float* __restrict__ s, float* __restrict__ d,
                                int rows, int cols)
{
  int i = blockIdx.x * blockDim.x + threadIdx.x;
  if (i < rows * cols) { int r = i / cols, c = i - r * cols; d[c * rows + r] = s[i]; }
}

// patch gather + relu(t@w1T)+relu(.@w2T) + sinusoidal PE -> z bf16 [16384,128]
__global__ __launch_bounds__(64)
void tokenizer_k(const float* __restrict__ x, const float* __restrict__ w1T,
                 const float* __restrict__ b1, const float* __restrict__ w2T,
                 const float* __restrict__ b2, u16* __restrict__ z)
{
  const int token = blockIdx.x;             // b*1024 + s
  const int b = token >> 10, s = token & 1023;
  const int ph = s >> 5, pw = s & 31;
  const int lane = threadIdx.x;
  __shared__ float t[320];
  __shared__ float z1[64];
  const int py = lane >> 3, px = lane & 7;
  const float* xp = x + (size_t)b * 5 * 65536 + (size_t)(ph * 8 + py) * 256 + pw * 8 + px;
#pragma unroll
  for (int c = 0; c < 5; ++c) t[c * 64 + lane] = xp[(size_t)c * 65536];
  __syncthreads();
  float acc = b1[lane];
  for (int k = 0; k < 320; ++k) acc = fmaf(t[k], w1T[k * 64 + lane], acc);
  z1[lane] = fmaxf(acc, 0.f);
  __syncthreads();
  float a0 = b2[lane], a1 = b2[lane + 64];
  for (int k = 0; k < 64; ++k) {
    const float zv = z1[k];
    a0 = fmaf(zv, w2T[k * 128 + lane], a0);
    a1 = fmaf(zv, w2T[k * 128 + lane + 64], a1);
  }
  a0 = fmaxf(a0, 0.f); a1 = fmaxf(a1, 0.f);
  const float fs = (float)s;
  const int d0 = lane, d1 = lane + 64;
  const float div0 = expf(-logf(10000.f) * (float)(d0 & ~1) / 128.f);
  const float div1 = expf(-logf(10000.f) * (float)(d1 & ~1) / 128.f);
  const float pe0 = (d0 & 1) ? cosf(fs * div0) : sinf(fs * div0);
  const float pe1 = (d1 & 1) ? cosf(fs * div1) : sinf(fs * div1);
  z[(size_t)token * 128 + d0] = f2bf(a0 + pe0);
  z[(size_t)token * 128 + d1] = f2bf(a1 + pe1);
}

// V slice of qkv -> vT[z=b*4+h][d][s], LDS-tiled transpose
__global__ void transpose_v_k(const u16* __restrict__ qkv, u16* __restrict__ vT)
{
  __shared__ u16 tile[32][33];
  const int z = blockIdx.z;
  const int b = z >> 2, hh = z & 3;
  const int s0 = blockIdx.x * 32, d0 = blockIdx.y * 32;
  const int tx = threadIdx.x;
  for (int i = threadIdx.y; i < 32; i += 8)
    tile[i][tx] = qkv[(long long)(b * 1024 + s0 + i) * 1536 + 1024 + hh * 128 + d0 + tx];
  __syncthreads();
  for (int j = threadIdx.y; j < 32; j += 8)
    vT[((long long)z * 128 + d0 + j) * 1024 + s0 + tx] = tile[tx][j];
}

// in-place row softmax (1024 cols, bf16), applies scale before softmax.
// vectorized: each thread owns 4 CONTIGUOUS bf16 (8B/lane coalesced).
__global__ __launch_bounds__(256)
void softmax_k(u16* __restrict__ P, float scale)
{
  const long long row = blockIdx.x;
  u16* p = P + row * 1024;
  const int tid = threadIdx.x;
  u16x4 vv = *(const u16x4*)(p + tid * 4);
  float v[4];
#pragma unroll
  for (int j = 0; j < 4; ++j) v[j] = bf2f(vv[j]) * scale;
  __shared__ float red[256];
  float mx = fmaxf(fmaxf(v[0], v[1]), fmaxf(v[2], v[3]));
  red[tid] = mx; __syncthreads();
  for (int s = 128; s > 0; s >>= 1) { if (tid < s) red[tid] = fmaxf(red[tid], red[tid + s]); __syncthreads(); }
  mx = red[0]; __syncthreads();
  float sum = 0.f;
#pragma unroll
  for (int j = 0; j < 4; ++j) { v[j] = expf(v[j] - mx); sum += v[j]; }
  red[tid] = sum; __syncthreads();
  for (int s = 128; s > 0; s >>= 1) { if (tid < s) red[tid] += red[tid + s]; __syncthreads(); }
  const float inv = 1.f / red[0];
  u16x4 ov;
#pragma unroll
  for (int j = 0; j < 4; ++j) ov[j] = f2bf(v[j] * inv);
  *(u16x4*)(p + tid * 4) = ov;
}

// h = LN(h + a); writes h fp32 and bf16 copy
__global__ __launch_bounds__(256)
void ln_add_k(float* __restrict__ h, const float* __restrict__ a,
              const float* __restrict__ g, const float* __restrict__ b,
              u16* __restrict__ hbf)
{
  const long long t = blockIdx.x;
  const int tid = threadIdx.x;
  float* hp = h + t * 512;
  const float* ap = a + t * 512;
  const float x0 = hp[tid] + ap[tid];
  const float x1 = hp[tid + 256] + ap[tid + 256];
  __shared__ float r1[256], r2[256];
  r1[tid] = x0 + x1; r2[tid] = x0 * x0 + x1 * x1;
  __syncthreads();
  for (int s = 128; s > 0; s >>= 1) { if (tid < s) { r1[tid] += r1[tid + s]; r2[tid] += r2[tid + s]; } __syncthreads(); }
  const float mean = r1[0] * (1.f / 512.f);
  const float var  = r2[0] * (1.f / 512.f) - mean * mean;
  const float rstd = rsqrtf(var + 1e-5f);
  const float y0 = (x0 - mean) * rstd * g[tid] + b[tid];
  const float y1 = (x1 - mean) * rstd * g[tid + 256] + b[tid + 256];
  hp[tid] = y0; hp[tid + 256] = y1;
  hbf[t * 512 + tid] = f2bf(y0); hbf[t * 512 + tid + 256] = f2bf(y1);
}

// m = LN(h+macc, g1,b1); h = LN(h+m, g2,b2); writes h fp32 + bf16
__global__ __launch_bounds__(256)
void merge_ln_k(float* __restrict__ h, const float* __restrict__ macc,
                const float* __restrict__ g1, const float* __restrict__ b1,
                const float* __restrict__ g2, const float* __restrict__ b2,
                u16* __restrict__ hbf)
{
  const long long t = blockIdx.x;
  const int tid = threadIdx.x;
  float* hp = h + t * 512;
  const float* mp = macc + t * 512;
  const float hx0 = hp[tid], hx1 = hp[tid + 256];
  const float s0 = hx0 + mp[tid], s1 = hx1 + mp[tid + 256];
  __shared__ float r1[256], r2[256];
  r1[tid] = s0 + s1; r2[tid] = s0 * s0 + s1 * s1;
  __syncthreads();
  for (int s = 128; s > 0; s >>= 1) { if (tid < s) { r1[tid] += r1[tid + s]; r2[tid] += r2[tid + s]; } __syncthreads(); }
  float mean = r1[0] * (1.f / 512.f);
  float var  = r2[0] * (1.f / 512.f) - mean * mean;
  float rstd = rsqrtf(var + 1e-5f);
  const float m0v = (s0 - mean) * rstd * g1[tid] + b1[tid];
  const float m1v = (s1 - mean) * rstd * g1[tid + 256] + b1[tid + 256];
  const float z0 = hx0 + m0v, z1 = hx1 + m1v;
  __syncthreads();
  r1[tid] = z0 + z1; r2[tid] = z0 * z0 + z1 * z1;
  __syncthreads();
  for (int s = 128; s > 0; s >>= 1) { if (tid < s) { r1[tid] += r1[tid + s]; r2[tid] += r2[tid + s]; } __syncthreads(); }
  mean = r1[0] * (1.f / 512.f);
  var  = r2[0] * (1.f / 512.f) - mean * mean;
  rstd = rsqrtf(var + 1e-5f);
  const float y0 = (z0 - mean) * rstd * g2[tid] + b2[tid];
  const float y1 = (z1 - mean) * rstd * g2[tid + 256] + b2[tid + 256];
  hp[tid] = y0; hp[tid + 256] = y1;
  hbf[t * 512 + tid] = f2bf(y0); hbf[t * 512 + tid + 256] = f2bf(y1);
}

// per-token: spec router softmax + top2-normalized comb[6]; shared softmax sp[2]
__global__ __launch_bounds__(64)
void router_k(const float* __restrict__ h, const float* __restrict__ sw,
              const float* __restrict__ hw, float* __restrict__ comb,
              float* __restrict__ sp)
{
  const long long t = blockIdx.x;
  const int lane = threadIdx.x;
  const float* hp = h + t * 512;
  float v[8];
#pragma unroll
  for (int j = 0; j < 8; ++j) v[j] = hp[lane + j * 64];

  float lg[6];
#pragma unroll
  for (int e = 0; e < 6; ++e) {
    const float* w = sw + e * 512;
    float d = 0.f;
#pragma unroll
    for (int j = 0; j < 8; ++j) d += v[j] * w[lane + j * 64];
#pragma unroll
    for (int off = 32; off > 0; off >>= 1) d += __shfl_xor(d, off);
    lg[e] = d;
  }
  float mx = lg[0];
#pragma unroll
  for (int e = 1; e < 6; ++e) mx = fmaxf(mx, lg[e]);
  float pp[6]; float sum = 0.f;
#pragma unroll
  for (int e = 0; e < 6; ++e) { pp[e] = expf(lg[e] - mx); sum += pp[e]; }
  const float inv = 1.f / sum;
#pragma unroll
  for (int e = 0; e < 6; ++e) pp[e] *= inv;

  int i1 = 0; float p1 = pp[0];
#pragma unroll
  for (int e = 1; e < 6; ++e) if (pp[e] > p1) { p1 = pp[e]; i1 = e; }   // ties -> lower idx
  int i2 = -1; float p2 = -1.f;
#pragma unroll
  for (int e = 0; e < 6; ++e) if (e != i1 && pp[e] > p2) { p2 = pp[e]; i2 = e; }
  const float den = 1.f / (p1 + p2 + 1e-9f);
  if (lane == 0) {
#pragma unroll
    for (int e = 0; e < 6; ++e)
      comb[t * 6 + e] = (e == i1) ? p1 * den : ((e == i2) ? p2 * den : 0.f);
  }

  float l0 = 0.f, l1 = 0.f;
#pragma unroll
  for (int j = 0; j < 8; ++j) {
    l0 += v[j] * hw[lane + j * 64];
    l1 += v[j] * hw[512 + lane + j * 64];
  }
#pragma unroll
  for (int off = 32; off > 0; off >>= 1) { l0 += __shfl_xor(l0, off); l1 += __shfl_xor(l1, off); }
  const float m2 = fmaxf(l0, l1);
  const float e0 = expf(l0 - m2), e1 = expf(l1 - m2);
  const float si = 1.f / (e0 + e1);
  if (lane == 0) { sp[t * 2 + 0] = e0 * si; sp[t * 2 + 1] = e1 * si; }
}

// per-expert token lists from comb (order within an expert is irrelevant)
__global__ __launch_bounds__(256)
void build_lists_k(const float* __restrict__ comb, int* __restrict__ cnt,
                   int* __restrict__ idx)
{
  const int t = blockIdx.x * blockDim.x + threadIdx.x;
  if (t >= 16384) return;
#pragma unroll
  for (int e = 0; e < 6; ++e) {
    if (comb[(long long)t * 6 + e] > 0.f) {
      const int pos = atomicAdd(&cnt[e], 1);
      idx[e * 16384 + pos] = t;
    }
  }
}

// mean over S then logits = pooled @ cls_w.T + cls_b
__global__ __launch_bounds__(256)
void pool_cls_k(const float* __restrict__ h, const float* __restrict__ cw,
                const float* __restrict__ cb, float* __restrict__ out)
{
  const int b = blockIdx.x;
  const int tid = threadIdx.x;
  const float* hp = h + (size_t)b * 1024 * 512;
  float s0 = 0.f, s1 = 0.f;
  for (int s = 0; s < 1024; ++s) {
    s0 += hp[(size_t)s * 512 + tid];
    s1 += hp[(size_t)s * 512 + tid + 256];
  }
  __shared__ float pooled[512];
  pooled[tid] = s0 * (1.f / 1024.f); pooled[tid + 256] = s1 * (1.f / 1024.f);
  __syncthreads();
  __shared__ float red[256];
  for (int c = 0; c < 2; ++c) {
    const float d = pooled[tid] * cw[c * 512 + tid] + pooled[tid + 256] * cw[c * 512 + tid + 256];
    red[tid] = d; __syncthreads();
    for (int s = 128; s > 0; s >>= 1) { if (tid < s) red[tid] += red[tid + s]; __syncthreads(); }
    if (tid == 0) out[b * 2 + c] = red[0] + cb[c];
    __syncthreads();
  }
}

// ---------------------------------------------------------------------------
extern "C" void kernel_launch(void* const* d_in, const int* in_sizes, int n_in,
                              void* d_out, int out_size, void* d_ws, size_t ws_size,
                              hipStream_t stream)
{
  (void)in_sizes; (void)n_in; (void)out_size; (void)ws_size;
  const float* x      = (const float*)d_in[0];
  const float* tok_w1 = (const float*)d_in[1];
  const float* tok_b1 = (const float*)d_in[2];
  const float* tok_w2 = (const float*)d_in[3];
  const float* tok_b2 = (const float*)d_in[4];
  const float* proj_w = (const float*)d_in[5];
  const float* proj_b = (const float*)d_in[6];
  const float* wqkv   = (const float*)d_in[7];
  const float* bqkv   = (const float*)d_in[8];
  const float* wo     = (const float*)d_in[9];
  const float* bo     = (const float*)d_in[10];
  const float* ln1_g  = (const float*)d_in[11];
  const float* ln1_b  = (const float*)d_in[12];
  const float* srw    = (const float*)d_in[13];
  const float* sfc1w  = (const float*)d_in[14];
  const float* sfc1b  = (const float*)d_in[15];
  const float* sfc2w  = (const float*)d_in[16];
  const float* sfc2b  = (const float*)d_in[17];
  const float* hrw    = (const float*)d_in[18];
  const float* hfc1w  = (const float*)d_in[19];
  const float* hfc1b  = (const float*)d_in[20];
  const float* hfc2w  = (const float*)d_in[21];
  const float* hfc2b  = (const float*)d_in[22];
  const float* lnm_g  = (const float*)d_in[23];
  const float* lnm_b  = (const float*)d_in[24];
  const float* ln2_g  = (const float*)d_in[25];
  const float* ln2_b  = (const float*)d_in[26];
  const float* cls_w  = (const float*)d_in[27];
  const float* cls_b  = (const float*)d_in[28];

  char* ws = (char*)d_ws;
  size_t off = 0;
  auto alloc = [&](size_t bytes) -> char* {
    char* p = ws + off;
    off = (off + bytes + 255) & ~(size_t)255;
    return p;
  };

  // bf16 weight copies (re-created every call; inputs restored each launch)
  u16* proj_bf = (u16*)alloc((size_t)512 * 128 * 2);
  u16* qkvw_bf = (u16*)alloc((size_t)4 * 1536 * 512 * 2);
  u16* wow_bf  = (u16*)alloc((size_t)4 * 512 * 512 * 2);
  u16* sfc1_bf = (u16*)alloc((size_t)4 * 6 * 2048 * 512 * 2);
  u16* sfc2_bf = (u16*)alloc((size_t)4 * 6 * 512 * 2048 * 2);
  u16* hfc1_bf = (u16*)alloc((size_t)4 * 2 * 2048 * 512 * 2);
  u16* hfc2_bf = (u16*)alloc((size_t)4 * 2 * 512 * 2048 * 2);
  float* w1T   = (float*)alloc((size_t)320 * 64 * 4);
  float* w2T   = (float*)alloc((size_t)64 * 128 * 4);
  u16* zbf     = (u16*)alloc((size_t)16384 * 128 * 2);
  float* h     = (float*)alloc((size_t)16384 * 512 * 4);
  u16* hbf     = (u16*)alloc((size_t)16384 * 512 * 2);
  u16* vT      = (u16*)alloc((size_t)64 * 128 * 1024 * 2);
  u16* abf     = (u16*)alloc((size_t)16384 * 512 * 2);
  int* cnt     = (int*)alloc((size_t)6 * 4);
  int* idx     = (int*)alloc((size_t)6 * 16384 * 4);
  // regionA (67MB): scores chunk (32 bh x 1024 x 1024 bf16) / wo-out fp32 / hid bf16
  char* regA   = alloc((size_t)32 * 1024 * 1024 * 2);
  // regionB (50MB): qkv bf16 [16384,1536] / (moe_acc fp32 + comb + sp)
  char* regB   = alloc((size_t)16384 * 1536 * 2);
  u16*   scores = (u16*)regA;
  float* af32   = (float*)regA;
  u16*   hid    = (u16*)regA;
  u16*   qkv    = (u16*)regB;
  float* macc   = (float*)regB;
  float* comb   = (float*)(regB + (size_t)16384 * 512 * 4);
  float* sp     = (float*)(regB + (size_t)16384 * 512 * 4 + (size_t)16384 * 6 * 4);

  // ---- weight prep ----
  cast_bf16_k<<<4096, 256, 0, stream>>>(proj_w, proj_bf, 65536LL);
  cast_bf16_k<<<4096, 256, 0, stream>>>(wqkv,   qkvw_bf, 3145728LL);
  cast_bf16_k<<<4096, 256, 0, stream>>>(wo,     wow_bf,  1048576LL);
  cast_bf16_k<<<4096, 256, 0, stream>>>(sfc1w,  sfc1_bf, 25165824LL);
  cast_bf16_k<<<4096, 256, 0, stream>>>(sfc2w,  sfc2_bf, 25165824LL);
  cast_bf16_k<<<4096, 256, 0, stream>>>(hfc1w,  hfc1_bf, 8388608LL);
  cast_bf16_k<<<4096, 256, 0, stream>>>(hfc2w,  hfc2_bf, 8388608LL);
  transpose_f32_k<<<(20480 + 255) / 256, 256, 0, stream>>>(tok_w1, w1T, 64, 320);
  transpose_f32_k<<<(8192 + 255) / 256, 256, 0, stream>>>(tok_w2, w2T, 128, 64);

  // ---- tokenizer + PE -> z, proj -> h ----
  tokenizer_k<<<16384, 64, 0, stream>>>(x, w1T, tok_b1, w2T, tok_b2, zbf);
  run_gemm64<0, 0, 1>(stream, zbf, proj_bf, h, proj_b, nullptr, 0,
                      16384, 512, 128, 128, 128, 512, 1, 1, 0, 0, 0, 0, 0, 0);
  cast_bf16_k<<<4096, 256, 0, stream>>>(h, hbf, 8388608LL);

  for (int l = 0; l < 4; ++l) {
    // qkv (wide M -> 128^2 tile is fine: 1536 blocks)
    run_gemm<0, 1, 1>(stream, hbf, qkvw_bf + (size_t)l * 1536 * 512, qkv,
                      bqkv + l * 1536, nullptr, 0,
                      16384, 1536, 512, 512, 512, 1536, 1, 1, 0, 0, 0, 0, 0, 0);
    transpose_v_k<<<dim3(32, 4, 64), dim3(32, 8), 0, stream>>>(qkv, vT);
    // attention in 2 half-batch chunks (caps score buffer at 67MB)
    for (int c = 0; c < 2; ++c) {
      const u16* qb = qkv + (size_t)c * 8 * 1024 * 1536;
      run_gemm<0, 1, 0>(stream, qb, qb + 512, scores, nullptr, nullptr, 0,
                        1024, 1024, 128, 1536, 1536, 1024, 32, 4,
                        1024LL * 1536, 128, 1024LL * 1536, 128,
                        4LL * 1024 * 1024, 1024LL * 1024);
      softmax_k<<<32768, 256, 0, stream>>>(scores, 0.08838834764831845f);
      // PV is skinny (M=128): 64^2 tile -> grid (16,2,32)=1024 blocks
      run_gemm64<0, 1, 0>(stream, scores, vT + (size_t)c * 8 * 4 * 128 * 1024,
                          abf + (size_t)c * 8 * 1024 * 512, nullptr, nullptr, 0,
                          1024, 128, 1024, 1024, 1024, 512, 32, 4,
                          4LL * 1024 * 1024, 1024LL * 1024,
                          4LL * 128 * 1024, 128LL * 1024,
                          1024LL * 512, 128);
    }
    // output projection (skinny M=512): 64^2 tile -> 2048 blocks
    run_gemm64<0, 0, 1>(stream, abf, wow_bf + (size_t)l * 512 * 512, af32,
                        bo + l * 512, nullptr, 0,
                        16384, 512, 512, 512, 512, 512, 1, 1, 0, 0, 0, 0, 0, 0);
    hipMemsetAsync(macc, 0, (size_t)16384 * 512 * 4, stream);  // qkv dead now
    ln_add_k<<<16384, 256, 0, stream>>>(h, af32, ln1_g + l * 512, ln1_b + l * 512, hbf);
    router_k<<<16384, 64, 0, stream>>>(h, srw + (size_t)l * 6 * 512,
                                       hrw + (size_t)l * 2 * 512, comb, sp);
    hipMemsetAsync(cnt, 0, 6 * sizeof(int), stream);
    build_lists_k<<<64, 256, 0, stream>>>(comb, cnt, idx);
    // specific experts: sparse (top-2), gathered rows; identical math to ref
    for (int e = 0; e < 6; ++e) {
      const size_t wi = (size_t)(l * 6 + e);
      // fc1: gather A rows by token list, gelu, bf16 store (position space); 64^2 tile
      gemm_tile64<2, 1, 1, 1><<<dim3(256, 32, 1), dim3(256), 0, stream>>>(
          hbf, sfc1_bf + wi * 2048 * 512, hid,
          sfc1b + wi * 2048, nullptr, 0, idx + e * 16384, cnt + e, 0,
          512, 512, 2048, 512, 1, 0, 0, 0, 0, 0, 0);
      // fc2: 64^2 tile, z=1, NON-atomic scatter += (rows unique within dispatch)
      gemm_tile64<0, 3, 1, 0><<<dim3(256, 8, 1), dim3(256), 0, stream>>>(
          hid, sfc2_bf + wi * 512 * 2048, macc,
          sfc2b + wi * 512, comb + e, 6, idx + e * 16384, cnt + e, 0,
          2048, 2048, 512, 2048, 1, 0, 0, 0, 0, 0, 0);
    }
    // shared experts (dense): fc1 on 128^2 (2048 blocks); fc2 skinny -> 64^2 dense +=
    for (int e = 0; e < 2; ++e) {
      const size_t wi = (size_t)(l * 2 + e);
      run_gemm<2, 1, 1>(stream, hbf, hfc1_bf + wi * 2048 * 512, hid,
                        hfc1b + wi * 2048, nullptr, 0,
                        16384, 2048, 512, 512, 512, 2048, 1, 1, 0, 0, 0, 0, 0, 0);
      run_gemm64<0, 2, 1>(stream, hid, hfc2_bf + wi * 512 * 2048, macc,
                          hfc2b + wi * 512, sp + e, 2,
                          16384, 512, 2048, 2048, 2048, 512, 1, 1, 0, 0, 0, 0, 0, 0);
    }
    merge_ln_k<<<16384, 256, 0, stream>>>(h, macc, lnm_g + l * 512, lnm_b + l * 512,
                                          ln2_g + l * 512, ln2_b + l * 512, hbf);
  }

  pool_cls_k<<<16, 256, 0, stream>>>(h, cls_w, cls_b, (float*)d_out);
}